// Round 23
// baseline (5239.067 us; speedup 1.0000x reference)
//
#include <hip/hip_runtime.h>

#define LL 6
#define BB 8
#define TT 1024
#define CC 1024
#define HH 16
#define HS 64
#define VV 4096
#define BT (BB*TT)

typedef __attribute__((ext_vector_type(4))) float f32x4;
typedef __attribute__((ext_vector_type(8))) short bf16x8;

#define RAWBAR() do { \
  asm volatile("s_waitcnt lgkmcnt(0)" ::: "memory"); \
  __builtin_amdgcn_s_barrier(); \
  __builtin_amdgcn_sched_barrier(0); \
} while (0)

__device__ __forceinline__ float bf2f(unsigned short u) {
  union { unsigned int u; float f; } v; v.u = ((unsigned int)u) << 16; return v.f;
}
__device__ __forceinline__ unsigned short rne16(float f) {
  unsigned u = __float_as_uint(f);
  return (unsigned short)((u + 0x7fffu + ((u >> 16) & 1u)) >> 16);
}
__device__ __forceinline__ void gld16(const uint4* g, uint4* l) {
  __builtin_amdgcn_global_load_lds(
      (const __attribute__((address_space(1))) void*)g,
      (__attribute__((address_space(3))) void*)l, 16, 0, 0);
}

// ---------------- embedding ----------------
__global__ __launch_bounds__(256) void embed_kernel(
    const int* __restrict__ idx, const float* __restrict__ tok,
    const float* __restrict__ pos, float* __restrict__ x) {
  int bt = blockIdx.x;
  int t = bt & (TT - 1);
  int id = idx[bt];
  float4 te = reinterpret_cast<const float4*>(tok)[(size_t)id * (CC/4) + threadIdx.x];
  float4 pe = reinterpret_cast<const float4*>(pos)[(size_t)t * (CC/4) + threadIdx.x];
  float4 r; r.x = te.x+pe.x; r.y = te.y+pe.y; r.z = te.z+pe.z; r.w = te.w+pe.w;
  reinterpret_cast<float4*>(x)[(size_t)bt * (CC/4) + threadIdx.x] = r;
}

// ---- splits ----
struct Oct2 { uint4 p0, p1; };
__device__ __forceinline__ Oct2 split8_rne2(const float* f) {
  unsigned h0[8], h1[8];
  #pragma unroll
  for (int e = 0; e < 8; ++e) {
    h0[e] = rne16(f[e]);
    float r = f[e] - bf2f((unsigned short)h0[e]);
    h1[e] = rne16(r);
  }
  Oct2 o;
  o.p0 = make_uint4(h0[0]|(h0[1]<<16), h0[2]|(h0[3]<<16), h0[4]|(h0[5]<<16), h0[6]|(h0[7]<<16));
  o.p1 = make_uint4(h1[0]|(h1[1]<<16), h1[2]|(h1[3]<<16), h1[4]|(h1[5]<<16), h1[6]|(h1[7]<<16));
  return o;
}
__device__ __forceinline__ uint4 pack8_rne(const float* f) {
  unsigned h[8];
  #pragma unroll
  for (int e = 0; e < 8; ++e) h[e] = rne16(f[e]);
  return make_uint4(h[0]|(h[1]<<16), h[2]|(h[3]<<16), h[4]|(h[5]<<16), h[6]|(h[7]<<16));
}

// ---------------- FUSED layernorm + A-presplit (2-plane RNE, pre-swizzled) -------
__global__ __launch_bounds__(256) void lnsplit_kernel(
    const float* __restrict__ x, const float* __restrict__ g,
    const float* __restrict__ b, uint4* __restrict__ outp) {
  __shared__ float red[8];
  __shared__ float rowbuf[1024];
  int row = blockIdx.x, tid = threadIdx.x;
  float4 v = reinterpret_cast<const float4*>(x)[(size_t)row * (CC/4) + tid];
  float s  = v.x+v.y+v.z+v.w;
  float ss = v.x*v.x+v.y*v.y+v.z*v.z+v.w*v.w;
  #pragma unroll
  for (int off = 32; off; off >>= 1) { s += __shfl_xor(s, off); ss += __shfl_xor(ss, off); }
  if ((tid & 63) == 0) { red[tid>>6] = s; red[4+(tid>>6)] = ss; }
  __syncthreads();
  s  = red[0]+red[1]+red[2]+red[3];
  ss = red[4]+red[5]+red[6]+red[7];
  float mu = s * (1.f/CC);
  float rs = rsqrtf(ss*(1.f/CC) - mu*mu + 1e-5f);
  float4 gg = reinterpret_cast<const float4*>(g)[tid];
  float4 bb = reinterpret_cast<const float4*>(b)[tid];
  float4 o;
  o.x = (v.x-mu)*rs*gg.x + bb.x;
  o.y = (v.y-mu)*rs*gg.y + bb.y;
  o.z = (v.z-mu)*rs*gg.z + bb.z;
  o.w = (v.w-mu)*rs*gg.w + bb.w;
  *reinterpret_cast<float4*>(&rowbuf[tid*4]) = o;
  __syncthreads();
  if (tid < 128) {
    const size_t aPS = (size_t)128 * 16 * 512;
    int kt = tid >> 3, sl = tid & 7;
    int r = row & 63, mt = row >> 6;
    float f[8];
    #pragma unroll
    for (int e = 0; e < 8; ++e) f[e] = rowbuf[tid*8 + e];
    size_t di = ((size_t)(mt*16 + kt))*512 + r*8 + (sl ^ (r & 7));
    Oct2 ot = split8_rne2(f);
    outp[di] = ot.p0; outp[aPS+di] = ot.p1;
  }
}

// ---------------- FUSED layernorm + 1-plane presplit (final LN / logits) ---------
__global__ __launch_bounds__(256) void lnsplit1_kernel(
    const float* __restrict__ x, const float* __restrict__ g,
    const float* __restrict__ b, uint4* __restrict__ outp) {
  __shared__ float red[8];
  __shared__ float rowbuf[1024];
  int row = blockIdx.x, tid = threadIdx.x;
  float4 v = reinterpret_cast<const float4*>(x)[(size_t)row * (CC/4) + tid];
  float s  = v.x+v.y+v.z+v.w;
  float ss = v.x*v.x+v.y*v.y+v.z*v.z+v.w*v.w;
  #pragma unroll
  for (int off = 32; off; off >>= 1) { s += __shfl_xor(s, off); ss += __shfl_xor(ss, off); }
  if ((tid & 63) == 0) { red[tid>>6] = s; red[4+(tid>>6)] = ss; }
  __syncthreads();
  s  = red[0]+red[1]+red[2]+red[3];
  ss = red[4]+red[5]+red[6]+red[7];
  float mu = s * (1.f/CC);
  float rs = rsqrtf(ss*(1.f/CC) - mu*mu + 1e-5f);
  float4 gg = reinterpret_cast<const float4*>(g)[tid];
  float4 bb = reinterpret_cast<const float4*>(b)[tid];
  float4 o;
  o.x = (v.x-mu)*rs*gg.x + bb.x;
  o.y = (v.y-mu)*rs*gg.y + bb.y;
  o.z = (v.z-mu)*rs*gg.z + bb.z;
  o.w = (v.w-mu)*rs*gg.w + bb.w;
  *reinterpret_cast<float4*>(&rowbuf[tid*4]) = o;
  __syncthreads();
  if (tid < 128) {
    int kt = tid >> 3, sl = tid & 7;
    int r = row & 63, mt = row >> 6;
    float f[8];
    #pragma unroll
    for (int e = 0; e < 8; ++e) f[e] = rowbuf[tid*8 + e];
    size_t di = ((size_t)(mt*16 + kt))*512 + r*8 + (sl ^ (r & 7));
    outp[di] = pack8_rne(f);
  }
}

// ---------------- fused B pre-split for Wq/Wk/Wv/Wo (one dispatch) ----------------
__global__ __launch_bounds__(256) void bsplit4_kernel(
    const float* __restrict__ Wq, const float* __restrict__ Wk,
    const float* __restrict__ Wv, const float* __restrict__ Wo,
    uint4* __restrict__ bsQK, uint4* __restrict__ bsV, uint4* __restrict__ bsO) {
  int z = blockIdx.z;
  const float* Bw = (z == 0) ? Wq : (z == 1) ? Wk : (z == 2) ? Wv : Wo;
  uint4* outp = (z <= 1) ? bsQK : (z == 2) ? bsV : bsO;
  int ntile0 = (z == 1) ? 8 : 0;
  int ntTotal = (z <= 1) ? 16 : 8;
  int ntile = ntile0 + blockIdx.x, kt = blockIdx.y;
  size_t planeStride = (size_t)ntTotal * 16 * 1024;
  int tid = threadIdx.x;
  int bcol = tid & 127, bkcg = tid >> 7;
  #pragma unroll
  for (int g = 0; g < 4; ++g) {
    int kc = bkcg*4 + g;
    float f[8];
    #pragma unroll
    for (int j = 0; j < 8; ++j)
      f[j] = Bw[(size_t)(kt*64 + kc*8 + j) * CC + blockIdx.x*128 + bcol];
    size_t di = (((size_t)ntile * 16 + kt) * 8 + kc) * 128 + bcol;
    Oct2 o = split8_rne2(f);
    outp[di] = o.p0; outp[planeStride+di] = o.p1;
  }
}

// ---------------- B pre-split (W1/W2/logits) ----------------
template<int NP>
__global__ __launch_bounds__(256) void bsplit_kernel(
    const float* __restrict__ Bw, uint4* __restrict__ outp, int ldb,
    int ntile0, int ntTotal) {
  int ntile = ntile0 + blockIdx.x, kt = blockIdx.y;
  size_t planeStride = (size_t)ntTotal * gridDim.y * 1024;
  int tid = threadIdx.x;
  int bcol = tid & 127, bkcg = tid >> 7;
  #pragma unroll
  for (int g = 0; g < 4; ++g) {
    int kc = bkcg*4 + g;
    float f[8];
    #pragma unroll
    for (int j = 0; j < 8; ++j)
      f[j] = Bw[(size_t)(kt*64 + kc*8 + j) * ldb + blockIdx.x*128 + bcol];
    size_t di = (((size_t)ntile * gridDim.y + kt) * 8 + kc) * 128 + bcol;
    if (NP == 2) {
      Oct2 o = split8_rne2(f);
      outp[di] = o.p0; outp[planeStride+di] = o.p1;
    } else {
      outp[di] = pack8_rne(f);
    }
  }
}

// ---------------- 128x128 GEMM: double-buffered DMA staging, counted vmcnt -------
// T3/T4 minimum pipeline: stage(kt+1) issued before compute(kt); wait vmcnt(N)
// (N = loads of the in-flight next tile) + raw barrier; lgkm-only barrier at end.
// NP2: 128 KB LDS (1 block/CU); NP1: 64 KB.
template<int NP, int NM>
__global__ __launch_bounds__(256) void gemm128_kernel(
    const uint4* __restrict__ Asp, size_t aPS,
    const uint4* __restrict__ Bs,
    const float* __restrict__ bias, const float* __restrict__ res,
    float* __restrict__ outf, int K, int ldc, int relu,
    int ntile0, int ntTotal, int kt0, int ktTotal, int vtmode,
    uint4* __restrict__ kout) {
  __shared__ uint4 lds_all[2*NP*2048];
  int tid = threadIdx.x;
  int NYd8 = gridDim.y >> 3;
  int li = blockIdx.x + gridDim.x * blockIdx.y;
  int xcd = li & 7, j = li >> 3;
  int by = xcd + 8 * (j % NYd8);
  int bx = j / NYd8;
  int m0 = by * 128;
  int n0 = bx * 128;
  int ntg = ntile0 + bx;
  size_t bPS = (size_t)ntTotal * ktTotal * 1024;
  int lane = tid & 63, w = tid >> 6;
  int wm = w >> 1, wn = w & 1;
  int lr = lane & 15, lk = lane >> 4;
  int nkt = K >> 6;

  f32x4 acc[4][4];
  #pragma unroll
  for (int m = 0; m < 4; ++m)
    #pragma unroll
    for (int n = 0; n < 4; ++n)
      acc[m][n] = (f32x4){0.f, 0.f, 0.f, 0.f};

  // stage one K-tile into buffer dst (per-thread: NP2=16 gld16, NP1=8)
  auto STAGE = [&](int dst, int kt_) {
    uint4* la = lds_all + dst*(NP*2048);
    uint4* lb = la + NP*1024;
    #pragma unroll
    for (int p = 0; p < NP; ++p) {
      const uint4* s0 = Asp + p*aPS + ((size_t)(2*by)   * nkt + kt_)*512;
      const uint4* s1 = Asp + p*aPS + ((size_t)(2*by+1) * nkt + kt_)*512;
      #pragma unroll
      for (int i = 0; i < 2; ++i) {
        int ch = w*2 + i;
        gld16(s0 + ch*64 + lane, &la[p*1024 + ch*64]);
        gld16(s1 + ch*64 + lane, &la[p*1024 + 512 + ch*64]);
      }
      const uint4* sb = Bs + p*bPS + ((size_t)ntg * ktTotal + (kt0 + kt_))*1024;
      #pragma unroll
      for (int i = 0; i < 4; ++i) {
        int ch = w*4 + i;
        gld16(sb + ch*64 + lane, &lb[p*1024 + ch*64]);
      }
    }
  };

  STAGE(0, 0);
  for (int kt = 0; kt < nkt; ++kt) {
    int cur = kt & 1;
    bool pre = (kt + 1 < nkt);
    if (pre) STAGE(cur ^ 1, kt + 1);
    // wait for current tile's loads only (next tile's stay in flight)
    if (pre) {
      if (NP == 2) asm volatile("s_waitcnt vmcnt(16)" ::: "memory");
      else         asm volatile("s_waitcnt vmcnt(8)"  ::: "memory");
    } else {
      asm volatile("s_waitcnt vmcnt(0)" ::: "memory");
    }
    __builtin_amdgcn_s_barrier();
    __builtin_amdgcn_sched_barrier(0);

    uint4* la = lds_all + cur*(NP*2048);
    uint4* lb = la + NP*1024;
    __builtin_amdgcn_s_setprio(1);
    #pragma unroll
    for (int ks = 0; ks < 2; ++ks) {
      int kc = ks*4 + lk;
      bf16x8 af[NP][4], bfr[NP][4];
      #pragma unroll
      for (int m = 0; m < 4; ++m) {
        int row = wm*64 + m*16 + lr;
        int si = (row>>6)*512 + (row&63)*8 + (kc ^ (row & 7));
        #pragma unroll
        for (int p = 0; p < NP; ++p)
          af[p][m] = reinterpret_cast<const bf16x8*>(la + p*1024)[si];
      }
      #pragma unroll
      for (int n = 0; n < 4; ++n) {
        int si = kc*128 + wn*64 + n*16 + lr;
        #pragma unroll
        for (int p = 0; p < NP; ++p)
          bfr[p][n] = reinterpret_cast<const bf16x8*>(lb + p*1024)[si];
      }
      #pragma unroll
      for (int m = 0; m < 4; ++m)
        #pragma unroll
        for (int n = 0; n < 4; ++n) {
          acc[m][n] = __builtin_amdgcn_mfma_f32_16x16x32_bf16(af[0][m], bfr[0][n], acc[m][n], 0, 0, 0);
          if (NP == 2) {
            acc[m][n] = __builtin_amdgcn_mfma_f32_16x16x32_bf16(af[0][m], bfr[1][n], acc[m][n], 0, 0, 0);
            acc[m][n] = __builtin_amdgcn_mfma_f32_16x16x32_bf16(af[1][m], bfr[0][n], acc[m][n], 0, 0, 0);
            if (NM == 4)
              acc[m][n] = __builtin_amdgcn_mfma_f32_16x16x32_bf16(af[1][m], bfr[1][n], acc[m][n], 0, 0, 0);
          }
        }
    }
    __builtin_amdgcn_s_setprio(0);
    RAWBAR();   // all waves done reading buf[cur]; next-tile vmem stays in flight
  }

  if (vtmode == 1) {
    char* vb = (char*)outf;
    const size_t VPSb = (size_t)2048 * 512 * 16;
    #pragma unroll
    for (int m = 0; m < 4; ++m) {
      int row = m0 + wm*64 + m*16 + lk*4;
      int bq = row >> 10;
      int t  = row & (TT-1);
      int ktile = t >> 6, r = t & 63;
      int kc = r >> 3, toct0 = r & 7;
      #pragma unroll
      for (int n = 0; n < 4; ++n) {
        int col = n0 + wn*64 + n*16 + lr;
        int hh2 = col >> 6, d = col & 63;
        int tile = (bq*HH + hh2)*16 + ktile;
        int vi = kc*64 + ((d ^ (kc<<1)) & 63);
        unsigned p0[4], p1[4];
        #pragma unroll
        for (int j2 = 0; j2 < 4; ++j2) {
          float v = acc[m][n][j2];
          p0[j2] = rne16(v);
          p1[j2] = rne16(v - bf2f((unsigned short)p0[j2]));
        }
        uint2 w0 = make_uint2(p0[0]|(p0[1]<<16), p0[2]|(p0[3]<<16));
        uint2 w1 = make_uint2(p1[0]|(p1[1]<<16), p1[2]|(p1[3]<<16));
        char* base = vb + ((size_t)tile*512 + vi)*16 + toct0*2;
        *reinterpret_cast<uint2*>(base) = w0;
        *reinterpret_cast<uint2*>(base + VPSb) = w1;
      }
    }
  } else if (vtmode == 2) {
    float* bounce = (float*)lds_all;
    #pragma unroll
    for (int m = 0; m < 4; ++m)
      #pragma unroll
      for (int n = 0; n < 4; ++n) {
        int cl = wn*64 + n*16 + lr;
        float bv = bias[n0 + cl];
        #pragma unroll
        for (int j2 = 0; j2 < 4; ++j2) {
          int rl = wm*64 + m*16 + lk*4 + j2;
          bounce[rl*128 + cl] = fmaxf(acc[m][n][j2] + bv, 0.f);
        }
      }
    __syncthreads();
    uint4* a1p = (uint4*)outf;
    const size_t aPSa = (size_t)128 * 32 * 512;
    #pragma unroll
    for (int i = 0; i < 8; ++i) {
      int ot = tid + i*256;
      int r = ot >> 4, o = ot & 15;
      float f[8];
      #pragma unroll
      for (int e = 0; e < 8; ++e) f[e] = bounce[r*128 + o*8 + e];
      Oct2 o2 = split8_rne2(f);
      int mt = 2*by + (r>>6), rs = r & 63;
      int ktg = (n0 >> 6) + (o >> 3), sl = o & 7;
      size_t di = ((size_t)(mt*32 + ktg))*512 + rs*8 + (sl ^ (rs & 7));
      a1p[di] = o2.p0; a1p[aPSa + di] = o2.p1;
    }
  } else if (vtmode == 3 && ntg >= 8) {
    float* bounce = (float*)lds_all;
    #pragma unroll
    for (int m = 0; m < 4; ++m)
      #pragma unroll
      for (int n = 0; n < 4; ++n) {
        int cl = wn*64 + n*16 + lr;
        #pragma unroll
        for (int j2 = 0; j2 < 4; ++j2) {
          int rl = wm*64 + m*16 + lk*4 + j2;
          bounce[rl*128 + cl] = acc[m][n][j2];
        }
      }
    __syncthreads();
    const size_t KPSC = (size_t)2048 * 512;
    int bq = m0 >> 10;
    int kt0tok = (m0 & 1023) >> 6;
    int hh0 = (ntg - 8) * 2;
    #pragma unroll
    for (int i = 0; i < 8; ++i) {
      int u = tid + i*256;
      int r = u >> 4, oct = u & 15;
      int head = oct >> 3, sl = oct & 7;
      float f[8];
      #pragma unroll
      for (int e = 0; e < 8; ++e) f[e] = bounce[r*128 + head*64 + sl*8 + e];
      Oct2 o = split8_rne2(f);
      int rk = r & 63;
      int tile = (bq*HH + hh0 + head)*16 + kt0tok + (r >> 6);
      size_t di = (size_t)tile*512 + rk*8 + (sl ^ (rk & 7));
      kout[di] = o.p0; kout[KPSC + di] = o.p1;
    }
  } else {
    #pragma unroll
    for (int m = 0; m < 4; ++m) {
      #pragma unroll
      for (int n = 0; n < 4; ++n) {
        int col = n0 + wn*64 + n*16 + lr;
        float bv = bias ? bias[col] : 0.f;
        #pragma unroll
        for (int j2 = 0; j2 < 4; ++j2) {
          int row = m0 + wm*64 + m*16 + lk*4 + j2;
          float vv = acc[m][n][j2] + bv;
          if (relu) vv = fmaxf(vv, 0.f);
          size_t off = (size_t)row * ldc + col;
          if (res) vv += res[off];
          outf[off] = vv;
        }
      }
    }
  }
}

// ---------------- MFMA flash attention (R22-proven, unchanged) -------
__global__ __launch_bounds__(256) void attn_mfma_kernel(
    const float* __restrict__ qf, const uint4* __restrict__ Kp,
    const uint4* __restrict__ Vp, uint4* __restrict__ aout) {
  __shared__ uint4 K_lds[2][512];
  __shared__ uint4 V_lds[2][512];
  __shared__ unsigned P_lds[64*68];
  const size_t KPS = (size_t)2048 * 512;
  const size_t VPS = (size_t)2048 * 512;
  const size_t APS = (size_t)128 * 16 * 512;
  int tid = threadIdx.x, lane = tid & 63, w = tid >> 6;
  int i = blockIdx.x;
  int xcd = i & 7, qm = (i >> 3) & 15, ghi = i >> 7;
  int g = ghi*8 + xcd;
  int b = g >> 4, hh = g & 15, qt = 15 - qm;
  int lr = lane & 15, lk = lane >> 4;
  const size_t tok0 = (size_t)b * TT;
  const int tbase = (b*HH + hh)*16;

  bf16x8 qa[2][2];
  {
    const float* qp = qf + (tok0 + qt*64 + w*16 + lr) * 1024 + hh*HS;
    #pragma unroll
    for (int ks = 0; ks < 2; ++ks) {
      const float4* p4 = reinterpret_cast<const float4*>(qp + ks*32 + lk*8);
      float4 a = p4[0], c = p4[1];
      float f[8] = {a.x,a.y,a.z,a.w,c.x,c.y,c.z,c.w};
      Oct2 ot = split8_rne2(f);
      qa[ks][0] = *reinterpret_cast<bf16x8*>(&ot.p0);
      qa[ks][1] = *reinterpret_cast<bf16x8*>(&ot.p1);
    }
  }

  float mrow[4] = {-3.0e38f,-3.0e38f,-3.0e38f,-3.0e38f};
  float lrow[4] = {0.f,0.f,0.f,0.f};
  f32x4 oac[4];
  #pragma unroll
  for (int n = 0; n < 4; ++n) oac[n] = (f32x4){0.f,0.f,0.f,0.f};

  {
    const uint4* ksrc = Kp + (size_t)tbase*512;
    const uint4* vsrc = Vp + (size_t)tbase*512;
    #pragma unroll
    for (int p = 0; p < 2; ++p)
      #pragma unroll
      for (int i2 = 0; i2 < 2; ++i2) {
        int ch = w*2 + i2;
        gld16(ksrc + p*KPS + ch*64 + lane, &K_lds[p][ch*64]);
        gld16(vsrc + p*VPS + ch*64 + lane, &V_lds[p][ch*64]);
      }
  }

  for (int kt = 0; kt <= qt; ++kt) {
    __syncthreads();

    f32x4 sfr[4];
    #pragma unroll
    for (int nf = 0; nf < 4; ++nf) sfr[nf] = (f32x4){0.f,0.f,0.f,0.f};
    __builtin_amdgcn_s_setprio(1);
    #pragma unroll
    for (int ks = 0; ks < 2; ++ks) {
      int kc = ks*4 + lk;
      #pragma unroll
      for (int nf = 0; nf < 4; ++nf) {
        int row = nf*16 + lr;
        int si = row*8 + (kc ^ (row & 7));
        bf16x8 k0 = *reinterpret_cast<const bf16x8*>(&K_lds[0][si]);
        bf16x8 k1 = *reinterpret_cast<const bf16x8*>(&K_lds[1][si]);
        sfr[nf] = __builtin_amdgcn_mfma_f32_16x16x32_bf16(qa[ks][0], k0, sfr[nf], 0,0,0);
        sfr[nf] = __builtin_amdgcn_mfma_f32_16x16x32_bf16(qa[ks][0], k1, sfr[nf], 0,0,0);
        sfr[nf] = __builtin_amdgcn_mfma_f32_16x16x32_bf16(qa[ks][1], k0, sfr[nf], 0,0,0);
      }
    }
    __builtin_amdgcn_s_setprio(0);
    RAWBAR();

    if (kt < qt) {
      const uint4* ksrc = Kp + (size_t)(tbase + kt + 1)*512;
      #pragma unroll
      for (int p = 0; p < 2; ++p)
        #pragma unroll
        for (int i2 = 0; i2 < 2; ++i2) {
          int ch = w*2 + i2;
          gld16(ksrc + p*KPS + ch*64 + lane, &K_lds[p][ch*64]);
        }
    }

    #pragma unroll
    for (int nf = 0; nf < 4; ++nf)
      #pragma unroll
      for (int j = 0; j < 4; ++j) {
        float s = sfr[nf][j] * 8.0f;
        if (kt == qt && (nf*16 + lr) > (w*16 + lk*4 + j)) s = -3.0e38f;
        sfr[nf][j] = s;
      }
    float alpha[4], tsum[4];
    #pragma unroll
    for (int j = 0; j < 4; ++j) {
      float mx = fmaxf(fmaxf(sfr[0][j], sfr[1][j]), fmaxf(sfr[2][j], sfr[3][j]));
      mx = fmaxf(mx, __shfl_xor(mx, 1));
      mx = fmaxf(mx, __shfl_xor(mx, 2));
      mx = fmaxf(mx, __shfl_xor(mx, 4));
      mx = fmaxf(mx, __shfl_xor(mx, 8));
      float mnew = fmaxf(mrow[j], mx);
      alpha[j] = __expf(mrow[j] - mnew);
      mrow[j] = mnew;
      tsum[j] = 0.f;
    }
    #pragma unroll
    for (int nf = 0; nf < 4; ++nf)
      #pragma unroll
      for (int j = 0; j < 4; ++j) {
        float p = __expf(sfr[nf][j] - mrow[j]);
        tsum[j] += p;
        unsigned u = __float_as_uint(p);
        float r = p - __uint_as_float(u & 0xffff0000u);
        unsigned pw = (u & 0xffff0000u) | (__float_as_uint(r) >> 16);
        int qrow = w*16 + lk*4 + j;
        int kcol = nf*16 + lr;
        P_lds[qrow*68 + (((kcol>>3) ^ (qrow & 7)))*8 + (kcol & 7)] = pw;
      }
    #pragma unroll
    for (int j = 0; j < 4; ++j) {
      float ts = tsum[j];
      ts += __shfl_xor(ts, 1);
      ts += __shfl_xor(ts, 2);
      ts += __shfl_xor(ts, 4);
      ts += __shfl_xor(ts, 8);
      lrow[j] = lrow[j]*alpha[j] + ts;
      oac[0][j] *= alpha[j]; oac[1][j] *= alpha[j];
      oac[2][j] *= alpha[j]; oac[3][j] *= alpha[j];
    }
    RAWBAR();

    __builtin_amdgcn_s_setprio(1);
    #pragma unroll
    for (int ks = 0; ks < 2; ++ks) {
      int kc = ks*4 + lk;
      int prow = w*16 + lr;
      const uint4* pp4 = reinterpret_cast<const uint4*>(
          &P_lds[prow*68 + ((kc ^ (prow & 7)))*8]);
      uint4 pw0 = pp4[0], pw1 = pp4[1];
      uint4 phu, plu;
      phu.x = (pw0.x>>16) | (pw0.y & 0xffff0000u);
      phu.y = (pw0.z>>16) | (pw0.w & 0xffff0000u);
      phu.z = (pw1.x>>16) | (pw1.y & 0xffff0000u);
      phu.w = (pw1.z>>16) | (pw1.w & 0xffff0000u);
      plu.x = (pw0.x & 0xffffu) | (pw0.y << 16);
      plu.y = (pw0.z & 0xffffu) | (pw0.w << 16);
      plu.z = (pw1.x & 0xffffu) | (pw1.y << 16);
      plu.w = (pw1.z & 0xffffu) | (pw1.w << 16);
      bf16x8 ph = *reinterpret_cast<bf16x8*>(&phu);
      bf16x8 pl = *reinterpret_cast<bf16x8*>(&plu);
      #pragma unroll
      for (int nf2 = 0; nf2 < 4; ++nf2) {
        int d = nf2*16 + lr;
        int vi = kc*64 + ((d ^ (kc<<1)) & 63);
        bf16x8 vh = *reinterpret_cast<const bf16x8*>(&V_lds[0][vi]);
        bf16x8 vl = *reinterpret_cast<const bf16x8*>(&V_lds[1][vi]);
        oac[nf2] = __builtin_amdgcn_mfma_f32_16x16x32_bf16(ph, vh, oac[nf2], 0,0,0);
        oac[nf2] = __builtin_amdgcn_mfma_f32_16x16x32_bf16(ph, vl, oac[nf2], 0,0,0);
        oac[nf2] = __builtin_amdgcn_mfma_f32_16x16x32_bf16(pl, vh, oac[nf2], 0,0,0);
      }
    }
    __builtin_amdgcn_s_setprio(0);
    if (kt < qt) {
      RAWBAR();
      const uint4* vsrc = Vp + (size_t)(tbase + kt + 1)*512;
      #pragma unroll
      for (int p = 0; p < 2; ++p)
        #pragma unroll
        for (int i2 = 0; i2 < 2; ++i2) {
          int ch = w*2 + i2;
          gld16(vsrc + p*VPS + ch*64 + lane, &V_lds[p][ch*64]);
        }
    }
  }

  __syncthreads();
  float* Pf = (float*)P_lds;
  #pragma unroll
  for (int j = 0; j < 4; ++j) {
    float inv = 1.0f / lrow[j];
    #pragma unroll
    for (int nf2 = 0; nf2 < 4; ++nf2)
      Pf[(w*16 + lk*4 + j)*68 + nf2*16 + lr] = oac[nf2][j] * inv;
  }
  __syncthreads();
  int mtkt = (b*16 + qt)*16 + hh;
  #pragma unroll
  for (int i2 = 0; i2 < 2; ++i2) {
    int u = tid + i2*256;
    int r = u >> 3, sl = u & 7;
    float f[8];
    #pragma unroll
    for (int e = 0; e < 8; ++e) f[e] = Pf[r*68 + sl*8 + e];
    Oct2 o = split8_rne2(f);
    size_t di = (size_t)mtkt*512 + r*8 + (sl ^ (r & 7));
    aout[di] = o.p0; aout[APS + di] = o.p1;
  }
}

extern "C" void kernel_launch(void* const* d_in, const int* in_sizes, int n_in,
                              void* d_out, int out_size, void* d_ws, size_t ws_size,
                              hipStream_t stream) {
  const int*   idx  = (const int*)d_in[0];
  const float* tok  = (const float*)d_in[1];
  const float* pos  = (const float*)d_in[2];
  const float* Wq   = (const float*)d_in[3];
  const float* Wk   = (const float*)d_in[4];
  const float* Wv   = (const float*)d_in[5];
  const float* Wo   = (const float*)d_in[6];
  const float* bo   = (const float*)d_in[7];
  const float* ln1g = (const float*)d_in[8];
  const float* ln1b = (const float*)d_in[9];
  const float* ln2g = (const float*)d_in[10];
  const float* ln2b = (const float*)d_in[11];
  const float* W1   = (const float*)d_in[12];
  const float* b1   = (const float*)d_in[13];
  const float* W2   = (const float*)d_in[14];
  const float* b2   = (const float*)d_in[15];
  const float* lnfg = (const float*)d_in[16];
  const float* lnfb = (const float*)d_in[17];
  const float* lmw  = (const float*)d_in[18];
  const float* lmb  = (const float*)d_in[19];
  float* out = (float*)d_out;

  char* ob = (char*)d_out;
  float* x  = (float*)ob;
  float* vplanes = (float*)(ob + ((size_t)32<<20));
  float* qf = (float*)(ob + ((size_t)64<<20));
  uint4* Kp = (uint4*)(ob + ((size_t)96<<20));
  float* a1p = (float*)(ob + ((size_t)64<<20));
  char* wsb = (char*)d_ws;
  uint4* aspH  = (uint4*)wsb;
  uint4* bsQK  = (uint4*)(wsb + ((size_t)32<<20));
  uint4* bsV   = (uint4*)(wsb + ((size_t)40<<20));
  uint4* bsO   = (uint4*)(wsb + ((size_t)44<<20));
  uint4* aspH2 = (uint4*)wsb;
  uint4* aspH3 = (uint4*)wsb;
  uint4* bsW1  = (uint4*)(wsb + ((size_t)32<<20));
  uint4* bsW2  = (uint4*)(wsb + ((size_t)48<<20));
  uint4* hfp   = (uint4*)wsb;
  uint4* bsL   = (uint4*)(wsb + ((size_t)32<<20));
  const size_t aPSh = (size_t)128 * 16 * 512;
  const size_t aPSa = (size_t)128 * 32 * 512;

  dim3 blk(256);
  dim3 gQK(16, 64), gV(8, 64), gO(8, 64);
  dim3 gW1(16, 64), gW2(8, 64), gL(32, 64);
  dim3 s4(8, 16, 4), sW1(32, 16), sW2(8, 64), sLM(32, 16);

  embed_kernel<<<BT, blk, 0, stream>>>(idx, tok, pos, x);
  for (int l = 0; l < LL; ++l) {
    const float* Wq_l = Wq + (size_t)l*CC*CC;
    const float* Wk_l = Wk + (size_t)l*CC*CC;
    const float* Wv_l = Wv + (size_t)l*CC*CC;
    const float* Wo_l = Wo + (size_t)l*CC*CC;
    const float* W1_l = W1 + (size_t)l*CC*4*CC;
    const float* W2_l = W2 + (size_t)l*4*CC*CC;
    lnsplit_kernel<<<BT, blk, 0, stream>>>(x, ln1g + (size_t)l*CC, ln1b + (size_t)l*CC, aspH);
    bsplit4_kernel<<<s4, blk, 0, stream>>>(Wq_l, Wk_l, Wv_l, Wo_l, bsQK, bsV, bsO);
    gemm128_kernel<2,3><<<gQK, blk, 0, stream>>>(aspH, aPSh, bsQK,
        nullptr, nullptr, qf, CC, 1024, 0, 0, 16, 0, 16, 3, Kp);
    gemm128_kernel<2,3><<<gV, blk, 0, stream>>>(aspH, aPSh, bsV,
        nullptr, nullptr, vplanes, CC, CC, 0, 0, 8, 0, 16, 1, nullptr);
    attn_mfma_kernel<<<BB*HH*16, blk, 0, stream>>>(qf, Kp, (const uint4*)vplanes, aspH2);
    gemm128_kernel<2,3><<<gO, blk, 0, stream>>>(aspH2, aPSh, bsO,
        bo + (size_t)l*CC, x, x, CC, CC, 0, 0, 8, 0, 16, 0, nullptr);
    lnsplit_kernel<<<BT, blk, 0, stream>>>(x, ln2g + (size_t)l*CC, ln2b + (size_t)l*CC, aspH3);
    bsplit_kernel<2><<<sW1, blk, 0, stream>>>(W1_l, bsW1, 4*CC, 0, 32);
    bsplit_kernel<2><<<sW2, blk, 0, stream>>>(W2_l, bsW2, CC, 0, 8);
    gemm128_kernel<2,3><<<gW1, blk, 0, stream>>>(aspH3, aPSh, bsW1,
        b1 + (size_t)l*4*CC, nullptr, a1p, CC, 2048, 1, 0, 32, 0, 16, 2, nullptr);
    gemm128_kernel<2,3><<<gW2, blk, 0, stream>>>((const uint4*)a1p, aPSa, bsW2,
        b2 + (size_t)l*CC, x, x, 2048, CC, 0, 0, 8, 0, 64, 0, nullptr);
    gemm128_kernel<2,3><<<gW1, blk, 0, stream>>>(aspH3, aPSh, bsW1,
        b1 + (size_t)l*4*CC + 2048, nullptr, a1p, CC, 2048, 1, 16, 32, 0, 16, 2, nullptr);
    gemm128_kernel<2,3><<<gW2, blk, 0, stream>>>((const uint4*)a1p, aPSa, bsW2,
        nullptr, x, x, 2048, CC, 0, 0, 8, 32, 64, 0, nullptr);
  }
  lnsplit1_kernel<<<BT, blk, 0, stream>>>(x, lnfg, lnfb, hfp);
  bsplit_kernel<1><<<sLM, blk, 0, stream>>>(lmw, bsL, VV, 0, 32);
  gemm128_kernel<1,1><<<gL, blk, 0, stream>>>(hfp, aPSh, bsL,
      lmb, nullptr, out, CC, VV, 0, 0, 32, 0, 16, 0, nullptr);
}

// Round 24
// 4271.572 us; speedup vs baseline: 1.2265x; 1.2265x over previous
//
#include <hip/hip_runtime.h>

#define LL 6
#define BB 8
#define TT 1024
#define CC 1024
#define HH 16
#define HS 64
#define VV 4096
#define BT (BB*TT)

typedef __attribute__((ext_vector_type(4))) float f32x4;
typedef __attribute__((ext_vector_type(8))) short bf16x8;

#define RAWBAR() do { \
  asm volatile("s_waitcnt lgkmcnt(0)" ::: "memory"); \
  __builtin_amdgcn_s_barrier(); \
  __builtin_amdgcn_sched_barrier(0); \
} while (0)

__device__ __forceinline__ float bf2f(unsigned short u) {
  union { unsigned int u; float f; } v; v.u = ((unsigned int)u) << 16; return v.f;
}
__device__ __forceinline__ unsigned short rne16(float f) {
  unsigned u = __float_as_uint(f);
  return (unsigned short)((u + 0x7fffu + ((u >> 16) & 1u)) >> 16);
}
__device__ __forceinline__ void gld16(const uint4* g, uint4* l) {
  __builtin_amdgcn_global_load_lds(
      (const __attribute__((address_space(1))) void*)g,
      (__attribute__((address_space(3))) void*)l, 16, 0, 0);
}

// ---------------- embedding ----------------
__global__ __launch_bounds__(256) void embed_kernel(
    const int* __restrict__ idx, const float* __restrict__ tok,
    const float* __restrict__ pos, float* __restrict__ x) {
  int bt = blockIdx.x;
  int t = bt & (TT - 1);
  int id = idx[bt];
  float4 te = reinterpret_cast<const float4*>(tok)[(size_t)id * (CC/4) + threadIdx.x];
  float4 pe = reinterpret_cast<const float4*>(pos)[(size_t)t * (CC/4) + threadIdx.x];
  float4 r; r.x = te.x+pe.x; r.y = te.y+pe.y; r.z = te.z+pe.z; r.w = te.w+pe.w;
  reinterpret_cast<float4*>(x)[(size_t)bt * (CC/4) + threadIdx.x] = r;
}

// ---- splits ----
struct Oct2 { uint4 p0, p1; };
__device__ __forceinline__ Oct2 split8_rne2(const float* f) {
  unsigned h0[8], h1[8];
  #pragma unroll
  for (int e = 0; e < 8; ++e) {
    h0[e] = rne16(f[e]);
    float r = f[e] - bf2f((unsigned short)h0[e]);
    h1[e] = rne16(r);
  }
  Oct2 o;
  o.p0 = make_uint4(h0[0]|(h0[1]<<16), h0[2]|(h0[3]<<16), h0[4]|(h0[5]<<16), h0[6]|(h0[7]<<16));
  o.p1 = make_uint4(h1[0]|(h1[1]<<16), h1[2]|(h1[3]<<16), h1[4]|(h1[5]<<16), h1[6]|(h1[7]<<16));
  return o;
}
__device__ __forceinline__ uint4 pack8_rne(const float* f) {
  unsigned h[8];
  #pragma unroll
  for (int e = 0; e < 8; ++e) h[e] = rne16(f[e]);
  return make_uint4(h[0]|(h[1]<<16), h[2]|(h[3]<<16), h[4]|(h[5]<<16), h[6]|(h[7]<<16));
}

// ---------------- FUSED layernorm + A-presplit (2-plane RNE, pre-swizzled) -------
__global__ __launch_bounds__(256) void lnsplit_kernel(
    const float* __restrict__ x, const float* __restrict__ g,
    const float* __restrict__ b, uint4* __restrict__ outp) {
  __shared__ float red[8];
  __shared__ float rowbuf[1024];
  int row = blockIdx.x, tid = threadIdx.x;
  float4 v = reinterpret_cast<const float4*>(x)[(size_t)row * (CC/4) + tid];
  float s  = v.x+v.y+v.z+v.w;
  float ss = v.x*v.x+v.y*v.y+v.z*v.z+v.w*v.w;
  #pragma unroll
  for (int off = 32; off; off >>= 1) { s += __shfl_xor(s, off); ss += __shfl_xor(ss, off); }
  if ((tid & 63) == 0) { red[tid>>6] = s; red[4+(tid>>6)] = ss; }
  __syncthreads();
  s  = red[0]+red[1]+red[2]+red[3];
  ss = red[4]+red[5]+red[6]+red[7];
  float mu = s * (1.f/CC);
  float rs = rsqrtf(ss*(1.f/CC) - mu*mu + 1e-5f);
  float4 gg = reinterpret_cast<const float4*>(g)[tid];
  float4 bb = reinterpret_cast<const float4*>(b)[tid];
  float4 o;
  o.x = (v.x-mu)*rs*gg.x + bb.x;
  o.y = (v.y-mu)*rs*gg.y + bb.y;
  o.z = (v.z-mu)*rs*gg.z + bb.z;
  o.w = (v.w-mu)*rs*gg.w + bb.w;
  *reinterpret_cast<float4*>(&rowbuf[tid*4]) = o;
  __syncthreads();
  if (tid < 128) {
    const size_t aPS = (size_t)128 * 16 * 512;
    int kt = tid >> 3, sl = tid & 7;
    int r = row & 63, mt = row >> 6;
    float f[8];
    #pragma unroll
    for (int e = 0; e < 8; ++e) f[e] = rowbuf[tid*8 + e];
    size_t di = ((size_t)(mt*16 + kt))*512 + r*8 + (sl ^ (r & 7));
    Oct2 ot = split8_rne2(f);
    outp[di] = ot.p0; outp[aPS+di] = ot.p1;
  }
}

// ---------------- FUSED layernorm + 1-plane presplit (final LN / logits) ---------
__global__ __launch_bounds__(256) void lnsplit1_kernel(
    const float* __restrict__ x, const float* __restrict__ g,
    const float* __restrict__ b, uint4* __restrict__ outp) {
  __shared__ float red[8];
  __shared__ float rowbuf[1024];
  int row = blockIdx.x, tid = threadIdx.x;
  float4 v = reinterpret_cast<const float4*>(x)[(size_t)row * (CC/4) + tid];
  float s  = v.x+v.y+v.z+v.w;
  float ss = v.x*v.x+v.y*v.y+v.z*v.z+v.w*v.w;
  #pragma unroll
  for (int off = 32; off; off >>= 1) { s += __shfl_xor(s, off); ss += __shfl_xor(ss, off); }
  if ((tid & 63) == 0) { red[tid>>6] = s; red[4+(tid>>6)] = ss; }
  __syncthreads();
  s  = red[0]+red[1]+red[2]+red[3];
  ss = red[4]+red[5]+red[6]+red[7];
  float mu = s * (1.f/CC);
  float rs = rsqrtf(ss*(1.f/CC) - mu*mu + 1e-5f);
  float4 gg = reinterpret_cast<const float4*>(g)[tid];
  float4 bb = reinterpret_cast<const float4*>(b)[tid];
  float4 o;
  o.x = (v.x-mu)*rs*gg.x + bb.x;
  o.y = (v.y-mu)*rs*gg.y + bb.y;
  o.z = (v.z-mu)*rs*gg.z + bb.z;
  o.w = (v.w-mu)*rs*gg.w + bb.w;
  *reinterpret_cast<float4*>(&rowbuf[tid*4]) = o;
  __syncthreads();
  if (tid < 128) {
    int kt = tid >> 3, sl = tid & 7;
    int r = row & 63, mt = row >> 6;
    float f[8];
    #pragma unroll
    for (int e = 0; e < 8; ++e) f[e] = rowbuf[tid*8 + e];
    size_t di = ((size_t)(mt*16 + kt))*512 + r*8 + (sl ^ (r & 7));
    outp[di] = pack8_rne(f);
  }
}

// ---------------- fused B pre-split for Wq/Wk/Wv/Wo (one dispatch) ----------------
__global__ __launch_bounds__(256) void bsplit4_kernel(
    const float* __restrict__ Wq, const float* __restrict__ Wk,
    const float* __restrict__ Wv, const float* __restrict__ Wo,
    uint4* __restrict__ bsQK, uint4* __restrict__ bsV, uint4* __restrict__ bsO) {
  int z = blockIdx.z;
  const float* Bw = (z == 0) ? Wq : (z == 1) ? Wk : (z == 2) ? Wv : Wo;
  uint4* outp = (z <= 1) ? bsQK : (z == 2) ? bsV : bsO;
  int ntile0 = (z == 1) ? 8 : 0;
  int ntTotal = (z <= 1) ? 16 : 8;
  int ntile = ntile0 + blockIdx.x, kt = blockIdx.y;
  size_t planeStride = (size_t)ntTotal * 16 * 1024;
  int tid = threadIdx.x;
  int bcol = tid & 127, bkcg = tid >> 7;
  #pragma unroll
  for (int g = 0; g < 4; ++g) {
    int kc = bkcg*4 + g;
    float f[8];
    #pragma unroll
    for (int j = 0; j < 8; ++j)
      f[j] = Bw[(size_t)(kt*64 + kc*8 + j) * CC + blockIdx.x*128 + bcol];
    size_t di = (((size_t)ntile * 16 + kt) * 8 + kc) * 128 + bcol;
    Oct2 o = split8_rne2(f);
    outp[di] = o.p0; outp[planeStride+di] = o.p1;
  }
}

// ---------------- B pre-split (W1/W2/logits) ----------------
template<int NP>
__global__ __launch_bounds__(256) void bsplit_kernel(
    const float* __restrict__ Bw, uint4* __restrict__ outp, int ldb,
    int ntile0, int ntTotal) {
  int ntile = ntile0 + blockIdx.x, kt = blockIdx.y;
  size_t planeStride = (size_t)ntTotal * gridDim.y * 1024;
  int tid = threadIdx.x;
  int bcol = tid & 127, bkcg = tid >> 7;
  #pragma unroll
  for (int g = 0; g < 4; ++g) {
    int kc = bkcg*4 + g;
    float f[8];
    #pragma unroll
    for (int j = 0; j < 8; ++j)
      f[j] = Bw[(size_t)(kt*64 + kc*8 + j) * ldb + blockIdx.x*128 + bcol];
    size_t di = (((size_t)ntile * gridDim.y + kt) * 8 + kc) * 128 + bcol;
    if (NP == 2) {
      Oct2 o = split8_rne2(f);
      outp[di] = o.p0; outp[planeStride+di] = o.p1;
    } else {
      outp[di] = pack8_rne(f);
    }
  }
}

// ---------------- 128x128 GEMM, global_load_lds staging, XCD-grouped grid -------
// (R22-proven: both planes DMA-staged into 64 KB LDS, 2-barrier loop)
template<int NP, bool ASP, int NM>
__global__ __launch_bounds__(256) void gemm128_kernel(
    const float* __restrict__ A, int lda,
    const uint4* __restrict__ Asp, size_t aPS,
    const uint4* __restrict__ Bs,
    const float* __restrict__ bias, const float* __restrict__ res,
    float* __restrict__ outf, int K, int ldc, int relu,
    int ntile0, int ntTotal, int kt0, int ktTotal, int vtmode,
    uint4* __restrict__ kout) {
  __shared__ uint4 lds_all[NP*2048];
  uint4* lds_a = lds_all;
  uint4* lds_b = lds_all + NP*1024;
  int tid = threadIdx.x;
  int NYd8 = gridDim.y >> 3;
  int li = blockIdx.x + gridDim.x * blockIdx.y;
  int xcd = li & 7, j = li >> 3;
  int by = xcd + 8 * (j % NYd8);
  int bx = j / NYd8;
  int m0 = by * 128;
  int n0 = bx * 128;
  int ntg = ntile0 + bx;
  size_t bPS = (size_t)ntTotal * ktTotal * 1024;
  int lane = tid & 63, w = tid >> 6;
  int wm = w >> 1, wn = w & 1;
  int lr = lane & 15, lk = lane >> 4;
  int nkt = K >> 6;

  f32x4 acc[4][4];
  #pragma unroll
  for (int m = 0; m < 4; ++m)
    #pragma unroll
    for (int n = 0; n < 4; ++n)
      acc[m][n] = (f32x4){0.f, 0.f, 0.f, 0.f};

  for (int kt = 0; kt < nkt; ++kt) {
    if (ASP) {
      #pragma unroll
      for (int p = 0; p < NP; ++p) {
        const uint4* s0 = Asp + p*aPS + ((size_t)(2*by)   * nkt + kt)*512;
        const uint4* s1 = Asp + p*aPS + ((size_t)(2*by+1) * nkt + kt)*512;
        #pragma unroll
        for (int i = 0; i < 2; ++i) {
          int ch = w*2 + i;
          gld16(s0 + ch*64 + lane, &lds_a[p*1024 + ch*64]);
          gld16(s1 + ch*64 + lane, &lds_a[p*1024 + 512 + ch*64]);
        }
      }
    } else {
      #pragma unroll
      for (int i = 0; i < 4; ++i) {
        int c = tid + i * 256;
        int row = c >> 3, sl = c & 7;
        const float4* ap = reinterpret_cast<const float4*>(
            A + (size_t)(m0+row)*lda + kt*64 + sl*8);
        float4 x0 = ap[0], x1 = ap[1];
        float f[8] = {x0.x,x0.y,x0.z,x0.w,x1.x,x1.y,x1.z,x1.w};
        int di = (row>>6)*512 + (row&63)*8 + (sl ^ (row & 7));
        if (NP == 2) {
          Oct2 o = split8_rne2(f);
          lds_a[di] = o.p0; lds_a[1024 + di] = o.p1;
        } else {
          lds_a[di] = pack8_rne(f);
        }
      }
    }
    {
      int ktg = kt0 + kt;
      #pragma unroll
      for (int p = 0; p < NP; ++p) {
        const uint4* sb = Bs + p*bPS + ((size_t)ntg * ktTotal + ktg)*1024;
        #pragma unroll
        for (int i = 0; i < 4; ++i) {
          int ch = w*4 + i;
          gld16(sb + ch*64 + lane, &lds_b[p*1024 + ch*64]);
        }
      }
    }
    __syncthreads();
    #pragma unroll
    for (int ks = 0; ks < 2; ++ks) {
      int kc = ks*4 + lk;
      bf16x8 af[NP][4], bfr[NP][4];
      #pragma unroll
      for (int m = 0; m < 4; ++m) {
        int row = wm*64 + m*16 + lr;
        int si = (row>>6)*512 + (row&63)*8 + (kc ^ (row & 7));
        #pragma unroll
        for (int p = 0; p < NP; ++p)
          af[p][m] = reinterpret_cast<const bf16x8*>(lds_a + p*1024)[si];
      }
      #pragma unroll
      for (int n = 0; n < 4; ++n) {
        int si = kc*128 + wn*64 + n*16 + lr;
        #pragma unroll
        for (int p = 0; p < NP; ++p)
          bfr[p][n] = reinterpret_cast<const bf16x8*>(lds_b + p*1024)[si];
      }
      #pragma unroll
      for (int m = 0; m < 4; ++m)
        #pragma unroll
        for (int n = 0; n < 4; ++n) {
          acc[m][n] = __builtin_amdgcn_mfma_f32_16x16x32_bf16(af[0][m], bfr[0][n], acc[m][n], 0, 0, 0);
          if (NP == 2) {
            acc[m][n] = __builtin_amdgcn_mfma_f32_16x16x32_bf16(af[0][m], bfr[1][n], acc[m][n], 0, 0, 0);
            acc[m][n] = __builtin_amdgcn_mfma_f32_16x16x32_bf16(af[1][m], bfr[0][n], acc[m][n], 0, 0, 0);
            if (NM == 4)
              acc[m][n] = __builtin_amdgcn_mfma_f32_16x16x32_bf16(af[1][m], bfr[1][n], acc[m][n], 0, 0, 0);
          }
        }
    }
    __syncthreads();
  }

  if (vtmode == 1) {
    char* vb = (char*)outf;
    const size_t VPSb = (size_t)2048 * 512 * 16;
    #pragma unroll
    for (int m = 0; m < 4; ++m) {
      int row = m0 + wm*64 + m*16 + lk*4;
      int bq = row >> 10;
      int t  = row & (TT-1);
      int ktile = t >> 6, r = t & 63;
      int kc = r >> 3, toct0 = r & 7;
      #pragma unroll
      for (int n = 0; n < 4; ++n) {
        int col = n0 + wn*64 + n*16 + lr;
        int hh2 = col >> 6, d = col & 63;
        int tile = (bq*HH + hh2)*16 + ktile;
        int vi = kc*64 + ((d ^ (kc<<1)) & 63);
        unsigned p0[4], p1[4];
        #pragma unroll
        for (int j2 = 0; j2 < 4; ++j2) {
          float v = acc[m][n][j2];
          p0[j2] = rne16(v);
          p1[j2] = rne16(v - bf2f((unsigned short)p0[j2]));
        }
        uint2 w0 = make_uint2(p0[0]|(p0[1]<<16), p0[2]|(p0[3]<<16));
        uint2 w1 = make_uint2(p1[0]|(p1[1]<<16), p1[2]|(p1[3]<<16));
        char* base = vb + ((size_t)tile*512 + vi)*16 + toct0*2;
        *reinterpret_cast<uint2*>(base) = w0;
        *reinterpret_cast<uint2*>(base + VPSb) = w1;
      }
    }
  } else if (vtmode == 2) {
    float* bounce = (float*)lds_all;
    #pragma unroll
    for (int m = 0; m < 4; ++m)
      #pragma unroll
      for (int n = 0; n < 4; ++n) {
        int cl = wn*64 + n*16 + lr;
        float bv = bias[n0 + cl];
        #pragma unroll
        for (int j2 = 0; j2 < 4; ++j2) {
          int rl = wm*64 + m*16 + lk*4 + j2;
          bounce[rl*128 + cl] = fmaxf(acc[m][n][j2] + bv, 0.f);
        }
      }
    __syncthreads();
    uint4* a1p = (uint4*)outf;
    const size_t aPSa = (size_t)128 * 32 * 512;
    #pragma unroll
    for (int i = 0; i < 8; ++i) {
      int ot = tid + i*256;
      int r = ot >> 4, o = ot & 15;
      float f[8];
      #pragma unroll
      for (int e = 0; e < 8; ++e) f[e] = bounce[r*128 + o*8 + e];
      Oct2 o2 = split8_rne2(f);
      int mt = 2*by + (r>>6), rs = r & 63;
      int ktg = (n0 >> 6) + (o >> 3), sl = o & 7;
      size_t di = ((size_t)(mt*32 + ktg))*512 + rs*8 + (sl ^ (rs & 7));
      a1p[di] = o2.p0; a1p[aPSa + di] = o2.p1;
    }
  } else if (vtmode == 3 && ntg >= 8) {
    float* bounce = (float*)lds_all;
    #pragma unroll
    for (int m = 0; m < 4; ++m)
      #pragma unroll
      for (int n = 0; n < 4; ++n) {
        int cl = wn*64 + n*16 + lr;
        #pragma unroll
        for (int j2 = 0; j2 < 4; ++j2) {
          int rl = wm*64 + m*16 + lk*4 + j2;
          bounce[rl*128 + cl] = acc[m][n][j2];
        }
      }
    __syncthreads();
    const size_t KPSC = (size_t)2048 * 512;
    int bq = m0 >> 10;
    int kt0tok = (m0 & 1023) >> 6;
    int hh0 = (ntg - 8) * 2;
    #pragma unroll
    for (int i = 0; i < 8; ++i) {
      int u = tid + i*256;
      int r = u >> 4, oct = u & 15;
      int head = oct >> 3, sl = oct & 7;
      float f[8];
      #pragma unroll
      for (int e = 0; e < 8; ++e) f[e] = bounce[r*128 + head*64 + sl*8 + e];
      Oct2 o = split8_rne2(f);
      int rk = r & 63;
      int tile = (bq*HH + hh0 + head)*16 + kt0tok + (r >> 6);
      size_t di = (size_t)tile*512 + rk*8 + (sl ^ (rk & 7));
      kout[di] = o.p0; kout[KPSC + di] = o.p1;
    }
  } else {
    #pragma unroll
    for (int m = 0; m < 4; ++m) {
      #pragma unroll
      for (int n = 0; n < 4; ++n) {
        int col = n0 + wn*64 + n*16 + lr;
        float bv = bias ? bias[col] : 0.f;
        #pragma unroll
        for (int j2 = 0; j2 < 4; ++j2) {
          int row = m0 + wm*64 + m*16 + lk*4 + j2;
          float vv = acc[m][n][j2] + bv;
          if (relu) vv = fmaxf(vv, 0.f);
          size_t off = (size_t)row * ldc + col;
          if (res) vv += res[off];
          outf[off] = vv;
        }
      }
    }
  }
}

// ---------------- MFMA flash attention: pipelined K-prefetch, raw barriers, setprio
__global__ __launch_bounds__(256) void attn_mfma_kernel(
    const float* __restrict__ qf, const uint4* __restrict__ Kp,
    const uint4* __restrict__ Vp, uint4* __restrict__ aout) {
  __shared__ uint4 K_lds[2][512];
  __shared__ uint4 V_lds[2][512];
  __shared__ unsigned P_lds[64*68];
  const size_t KPS = (size_t)2048 * 512;
  const size_t VPS = (size_t)2048 * 512;
  const size_t APS = (size_t)128 * 16 * 512;
  int tid = threadIdx.x, lane = tid & 63, w = tid >> 6;
  int i = blockIdx.x;
  int xcd = i & 7, qm = (i >> 3) & 15, ghi = i >> 7;
  int g = ghi*8 + xcd;
  int b = g >> 4, hh = g & 15, qt = 15 - qm;
  int lr = lane & 15, lk = lane >> 4;
  const size_t tok0 = (size_t)b * TT;
  const int tbase = (b*HH + hh)*16;

  bf16x8 qa[2][2];
  {
    const float* qp = qf + (tok0 + qt*64 + w*16 + lr) * 1024 + hh*HS;
    #pragma unroll
    for (int ks = 0; ks < 2; ++ks) {
      const float4* p4 = reinterpret_cast<const float4*>(qp + ks*32 + lk*8);
      float4 a = p4[0], c = p4[1];
      float f[8] = {a.x,a.y,a.z,a.w,c.x,c.y,c.z,c.w};
      Oct2 ot = split8_rne2(f);
      qa[ks][0] = *reinterpret_cast<bf16x8*>(&ot.p0);
      qa[ks][1] = *reinterpret_cast<bf16x8*>(&ot.p1);
    }
  }

  float mrow[4] = {-3.0e38f,-3.0e38f,-3.0e38f,-3.0e38f};
  float lrow[4] = {0.f,0.f,0.f,0.f};
  f32x4 oac[4];
  #pragma unroll
  for (int n = 0; n < 4; ++n) oac[n] = (f32x4){0.f,0.f,0.f,0.f};

  {
    const uint4* ksrc = Kp + (size_t)tbase*512;
    const uint4* vsrc = Vp + (size_t)tbase*512;
    #pragma unroll
    for (int p = 0; p < 2; ++p)
      #pragma unroll
      for (int i2 = 0; i2 < 2; ++i2) {
        int ch = w*2 + i2;
        gld16(ksrc + p*KPS + ch*64 + lane, &K_lds[p][ch*64]);
        gld16(vsrc + p*VPS + ch*64 + lane, &V_lds[p][ch*64]);
      }
  }

  for (int kt = 0; kt <= qt; ++kt) {
    __syncthreads();

    f32x4 sfr[4];
    #pragma unroll
    for (int nf = 0; nf < 4; ++nf) sfr[nf] = (f32x4){0.f,0.f,0.f,0.f};
    __builtin_amdgcn_s_setprio(1);
    #pragma unroll
    for (int ks = 0; ks < 2; ++ks) {
      int kc = ks*4 + lk;
      #pragma unroll
      for (int nf = 0; nf < 4; ++nf) {
        int row = nf*16 + lr;
        int si = row*8 + (kc ^ (row & 7));
        bf16x8 k0 = *reinterpret_cast<const bf16x8*>(&K_lds[0][si]);
        bf16x8 k1 = *reinterpret_cast<const bf16x8*>(&K_lds[1][si]);
        sfr[nf] = __builtin_amdgcn_mfma_f32_16x16x32_bf16(qa[ks][0], k0, sfr[nf], 0,0,0);
        sfr[nf] = __builtin_amdgcn_mfma_f32_16x16x32_bf16(qa[ks][0], k1, sfr[nf], 0,0,0);
        sfr[nf] = __builtin_amdgcn_mfma_f32_16x16x32_bf16(qa[ks][1], k0, sfr[nf], 0,0,0);
      }
    }
    __builtin_amdgcn_s_setprio(0);
    RAWBAR();

    if (kt < qt) {
      const uint4* ksrc = Kp + (size_t)(tbase + kt + 1)*512;
      #pragma unroll
      for (int p = 0; p < 2; ++p)
        #pragma unroll
        for (int i2 = 0; i2 < 2; ++i2) {
          int ch = w*2 + i2;
          gld16(ksrc + p*KPS + ch*64 + lane, &K_lds[p][ch*64]);
        }
    }

    #pragma unroll
    for (int nf = 0; nf < 4; ++nf)
      #pragma unroll
      for (int j = 0; j < 4; ++j) {
        float s = sfr[nf][j] * 8.0f;
        if (kt == qt && (nf*16 + lr) > (w*16 + lk*4 + j)) s = -3.0e38f;
        sfr[nf][j] = s;
      }
    float alpha[4], tsum[4];
    #pragma unroll
    for (int j = 0; j < 4; ++j) {
      float mx = fmaxf(fmaxf(sfr[0][j], sfr[1][j]), fmaxf(sfr[2][j], sfr[3][j]));
      mx = fmaxf(mx, __shfl_xor(mx, 1));
      mx = fmaxf(mx, __shfl_xor(mx, 2));
      mx = fmaxf(mx, __shfl_xor(mx, 4));
      mx = fmaxf(mx, __shfl_xor(mx, 8));
      float mnew = fmaxf(mrow[j], mx);
      alpha[j] = __expf(mrow[j] - mnew);
      mrow[j] = mnew;
      tsum[j] = 0.f;
    }
    #pragma unroll
    for (int nf = 0; nf < 4; ++nf)
      #pragma unroll
      for (int j = 0; j < 4; ++j) {
        float p = __expf(sfr[nf][j] - mrow[j]);
        tsum[j] += p;
        unsigned u = __float_as_uint(p);
        float r = p - __uint_as_float(u & 0xffff0000u);
        unsigned pw = (u & 0xffff0000u) | (__float_as_uint(r) >> 16);
        int qrow = w*16 + lk*4 + j;
        int kcol = nf*16 + lr;
        P_lds[qrow*68 + (((kcol>>3) ^ (qrow & 7)))*8 + (kcol & 7)] = pw;
      }
    #pragma unroll
    for (int j = 0; j < 4; ++j) {
      float ts = tsum[j];
      ts += __shfl_xor(ts, 1);
      ts += __shfl_xor(ts, 2);
      ts += __shfl_xor(ts, 4);
      ts += __shfl_xor(ts, 8);
      lrow[j] = lrow[j]*alpha[j] + ts;
      oac[0][j] *= alpha[j]; oac[1][j] *= alpha[j];
      oac[2][j] *= alpha[j]; oac[3][j] *= alpha[j];
    }
    RAWBAR();

    __builtin_amdgcn_s_setprio(1);
    #pragma unroll
    for (int ks = 0; ks < 2; ++ks) {
      int kc = ks*4 + lk;
      int prow = w*16 + lr;
      const uint4* pp4 = reinterpret_cast<const uint4*>(
          &P_lds[prow*68 + ((kc ^ (prow & 7)))*8]);
      uint4 pw0 = pp4[0], pw1 = pp4[1];
      uint4 phu, plu;
      phu.x = (pw0.x>>16) | (pw0.y & 0xffff0000u);
      phu.y = (pw0.z>>16) | (pw0.w & 0xffff0000u);
      phu.z = (pw1.x>>16) | (pw1.y & 0xffff0000u);
      phu.w = (pw1.z>>16) | (pw1.w & 0xffff0000u);
      plu.x = (pw0.x & 0xffffu) | (pw0.y << 16);
      plu.y = (pw0.z & 0xffffu) | (pw0.w << 16);
      plu.z = (pw1.x & 0xffffu) | (pw1.y << 16);
      plu.w = (pw1.z & 0xffffu) | (pw1.w << 16);
      bf16x8 ph = *reinterpret_cast<bf16x8*>(&phu);
      bf16x8 pl = *reinterpret_cast<bf16x8*>(&plu);
      #pragma unroll
      for (int nf2 = 0; nf2 < 4; ++nf2) {
        int d = nf2*16 + lr;
        int vi = kc*64 + ((d ^ (kc<<1)) & 63);
        bf16x8 vh = *reinterpret_cast<const bf16x8*>(&V_lds[0][vi]);
        bf16x8 vl = *reinterpret_cast<const bf16x8*>(&V_lds[1][vi]);
        oac[nf2] = __builtin_amdgcn_mfma_f32_16x16x32_bf16(ph, vh, oac[nf2], 0,0,0);
        oac[nf2] = __builtin_amdgcn_mfma_f32_16x16x32_bf16(ph, vl, oac[nf2], 0,0,0);
        oac[nf2] = __builtin_amdgcn_mfma_f32_16x16x32_bf16(pl, vh, oac[nf2], 0,0,0);
      }
    }
    __builtin_amdgcn_s_setprio(0);
    if (kt < qt) {
      RAWBAR();
      const uint4* vsrc = Vp + (size_t)(tbase + kt + 1)*512;
      #pragma unroll
      for (int p = 0; p < 2; ++p)
        #pragma unroll
        for (int i2 = 0; i2 < 2; ++i2) {
          int ch = w*2 + i2;
          gld16(vsrc + p*VPS + ch*64 + lane, &V_lds[p][ch*64]);
        }
    }
  }

  __syncthreads();
  float* Pf = (float*)P_lds;
  #pragma unroll
  for (int j = 0; j < 4; ++j) {
    float inv = 1.0f / lrow[j];
    #pragma unroll
    for (int nf2 = 0; nf2 < 4; ++nf2)
      Pf[(w*16 + lk*4 + j)*68 + nf2*16 + lr] = oac[nf2][j] * inv;
  }
  __syncthreads();
  int mtkt = (b*16 + qt)*16 + hh;
  #pragma unroll
  for (int i2 = 0; i2 < 2; ++i2) {
    int u = tid + i2*256;
    int r = u >> 3, sl = u & 7;
    float f[8];
    #pragma unroll
    for (int e = 0; e < 8; ++e) f[e] = Pf[r*68 + sl*8 + e];
    Oct2 o = split8_rne2(f);
    size_t di = (size_t)mtkt*512 + r*8 + (sl ^ (r & 7));
    aout[di] = o.p0; aout[APS + di] = o.p1;
  }
}

extern "C" void kernel_launch(void* const* d_in, const int* in_sizes, int n_in,
                              void* d_out, int out_size, void* d_ws, size_t ws_size,
                              hipStream_t stream) {
  const int*   idx  = (const int*)d_in[0];
  const float* tok  = (const float*)d_in[1];
  const float* pos  = (const float*)d_in[2];
  const float* Wq   = (const float*)d_in[3];
  const float* Wk   = (const float*)d_in[4];
  const float* Wv   = (const float*)d_in[5];
  const float* Wo   = (const float*)d_in[6];
  const float* bo   = (const float*)d_in[7];
  const float* ln1g = (const float*)d_in[8];
  const float* ln1b = (const float*)d_in[9];
  const float* ln2g = (const float*)d_in[10];
  const float* ln2b = (const float*)d_in[11];
  const float* W1   = (const float*)d_in[12];
  const float* b1   = (const float*)d_in[13];
  const float* W2   = (const float*)d_in[14];
  const float* b2   = (const float*)d_in[15];
  const float* lnfg = (const float*)d_in[16];
  const float* lnfb = (const float*)d_in[17];
  const float* lmw  = (const float*)d_in[18];
  const float* lmb  = (const float*)d_in[19];
  float* out = (float*)d_out;

  char* ob = (char*)d_out;
  float* x  = (float*)ob;
  float* vplanes = (float*)(ob + ((size_t)32<<20));
  float* qf = (float*)(ob + ((size_t)64<<20));
  uint4* Kp = (uint4*)(ob + ((size_t)96<<20));
  float* a1p = (float*)(ob + ((size_t)64<<20));
  char* wsb = (char*)d_ws;
  uint4* aspH  = (uint4*)wsb;
  uint4* bsQK  = (uint4*)(wsb + ((size_t)32<<20));
  uint4* bsV   = (uint4*)(wsb + ((size_t)40<<20));
  uint4* bsO   = (uint4*)(wsb + ((size_t)44<<20));
  uint4* aspH2 = (uint4*)wsb;
  uint4* aspH3 = (uint4*)wsb;
  uint4* bsW1  = (uint4*)(wsb + ((size_t)32<<20));
  uint4* bsW2  = (uint4*)(wsb + ((size_t)48<<20));
  uint4* hfp   = (uint4*)wsb;
  uint4* bsL   = (uint4*)(wsb + ((size_t)32<<20));
  const size_t aPSh = (size_t)128 * 16 * 512;
  const size_t aPSa = (size_t)128 * 32 * 512;

  dim3 blk(256);
  dim3 gQK(16, 64), gV(8, 64), gO(8, 64);
  dim3 gW1(16, 64), gW2(8, 64), gL(32, 64);
  dim3 s4(8, 16, 4), sW1(32, 16), sW2(8, 64), sLM(32, 16);

  embed_kernel<<<BT, blk, 0, stream>>>(idx, tok, pos, x);
  for (int l = 0; l < LL; ++l) {
    const float* Wq_l = Wq + (size_t)l*CC*CC;
    const float* Wk_l = Wk + (size_t)l*CC*CC;
    const float* Wv_l = Wv + (size_t)l*CC*CC;
    const float* Wo_l = Wo + (size_t)l*CC*CC;
    const float* W1_l = W1 + (size_t)l*CC*4*CC;
    const float* W2_l = W2 + (size_t)l*4*CC*CC;
    lnsplit_kernel<<<BT, blk, 0, stream>>>(x, ln1g + (size_t)l*CC, ln1b + (size_t)l*CC, aspH);
    bsplit4_kernel<<<s4, blk, 0, stream>>>(Wq_l, Wk_l, Wv_l, Wo_l, bsQK, bsV, bsO);
    gemm128_kernel<2,true,3><<<gQK, blk, 0, stream>>>(nullptr, 0, aspH, aPSh, bsQK,
        nullptr, nullptr, qf, CC, 1024, 0, 0, 16, 0, 16, 3, Kp);
    gemm128_kernel<2,true,3><<<gV, blk, 0, stream>>>(nullptr, 0, aspH, aPSh, bsV,
        nullptr, nullptr, vplanes, CC, CC, 0, 0, 8, 0, 16, 1, nullptr);
    attn_mfma_kernel<<<BB*HH*16, blk, 0, stream>>>(qf, Kp, (const uint4*)vplanes, aspH2);
    gemm128_kernel<2,true,3><<<gO, blk, 0, stream>>>(nullptr, 0, aspH2, aPSh, bsO,
        bo + (size_t)l*CC, x, x, CC, CC, 0, 0, 8, 0, 16, 0, nullptr);
    lnsplit_kernel<<<BT, blk, 0, stream>>>(x, ln2g + (size_t)l*CC, ln2b + (size_t)l*CC, aspH3);
    bsplit_kernel<2><<<sW1, blk, 0, stream>>>(W1_l, bsW1, 4*CC, 0, 32);
    bsplit_kernel<2><<<sW2, blk, 0, stream>>>(W2_l, bsW2, CC, 0, 8);
    gemm128_kernel<2,true,3><<<gW1, blk, 0, stream>>>(nullptr, 0, aspH3, aPSh, bsW1,
        b1 + (size_t)l*4*CC, nullptr, a1p, CC, 2048, 1, 0, 32, 0, 16, 2, nullptr);
    gemm128_kernel<2,true,3><<<gW2, blk, 0, stream>>>(nullptr, 0, (const uint4*)a1p, aPSa, bsW2,
        b2 + (size_t)l*CC, x, x, 2048, CC, 0, 0, 8, 0, 64, 0, nullptr);
    gemm128_kernel<2,true,3><<<gW1, blk, 0, stream>>>(nullptr, 0, aspH3, aPSh, bsW1,
        b1 + (size_t)l*4*CC + 2048, nullptr, a1p, CC, 2048, 1, 16, 32, 0, 16, 2, nullptr);
    gemm128_kernel<2,true,3><<<gW2, blk, 0, stream>>>(nullptr, 0, (const uint4*)a1p, aPSa, bsW2,
        nullptr, x, x, 2048, CC, 0, 0, 8, 32, 64, 0, nullptr);
  }
  lnsplit1_kernel<<<BT, blk, 0, stream>>>(x, lnfg, lnfb, hfp);
  bsplit_kernel<1><<<sLM, blk, 0, stream>>>(lmw, bsL, VV, 0, 32);
  gemm128_kernel<1,true,1><<<gL, blk, 0, stream>>>(nullptr, 0, hfp, aPSh, bsL,
      lmb, nullptr, out, CC, VV, 0, 0, 32, 0, 16, 0, nullptr);
}

// Round 25
// 4241.278 us; speedup vs baseline: 1.2353x; 1.0071x over previous
//
#include <hip/hip_runtime.h>

#define LL 6
#define BB 8
#define TT 1024
#define CC 1024
#define HH 16
#define HS 64
#define VV 4096
#define BT (BB*TT)

typedef __attribute__((ext_vector_type(4))) float f32x4;
typedef __attribute__((ext_vector_type(8))) short bf16x8;

#define RAWBAR() do { \
  asm volatile("s_waitcnt lgkmcnt(0)" ::: "memory"); \
  __builtin_amdgcn_s_barrier(); \
  __builtin_amdgcn_sched_barrier(0); \
} while (0)

__device__ __forceinline__ float bf2f(unsigned short u) {
  union { unsigned int u; float f; } v; v.u = ((unsigned int)u) << 16; return v.f;
}
__device__ __forceinline__ unsigned short rne16(float f) {
  unsigned u = __float_as_uint(f);
  return (unsigned short)((u + 0x7fffu + ((u >> 16) & 1u)) >> 16);
}
__device__ __forceinline__ void gld16(const uint4* g, uint4* l) {
  __builtin_amdgcn_global_load_lds(
      (const __attribute__((address_space(1))) void*)g,
      (__attribute__((address_space(3))) void*)l, 16, 0, 0);
}

// ---------------- embedding ----------------
__global__ __launch_bounds__(256) void embed_kernel(
    const int* __restrict__ idx, const float* __restrict__ tok,
    const float* __restrict__ pos, float* __restrict__ x) {
  int bt = blockIdx.x;
  int t = bt & (TT - 1);
  int id = idx[bt];
  float4 te = reinterpret_cast<const float4*>(tok)[(size_t)id * (CC/4) + threadIdx.x];
  float4 pe = reinterpret_cast<const float4*>(pos)[(size_t)t * (CC/4) + threadIdx.x];
  float4 r; r.x = te.x+pe.x; r.y = te.y+pe.y; r.z = te.z+pe.z; r.w = te.w+pe.w;
  reinterpret_cast<float4*>(x)[(size_t)bt * (CC/4) + threadIdx.x] = r;
}

// ---- splits ----
struct Oct2 { uint4 p0, p1; };
__device__ __forceinline__ Oct2 split8_rne2(const float* f) {
  unsigned h0[8], h1[8];
  #pragma unroll
  for (int e = 0; e < 8; ++e) {
    h0[e] = rne16(f[e]);
    float r = f[e] - bf2f((unsigned short)h0[e]);
    h1[e] = rne16(r);
  }
  Oct2 o;
  o.p0 = make_uint4(h0[0]|(h0[1]<<16), h0[2]|(h0[3]<<16), h0[4]|(h0[5]<<16), h0[6]|(h0[7]<<16));
  o.p1 = make_uint4(h1[0]|(h1[1]<<16), h1[2]|(h1[3]<<16), h1[4]|(h1[5]<<16), h1[6]|(h1[7]<<16));
  return o;
}
__device__ __forceinline__ uint4 pack8_rne(const float* f) {
  unsigned h[8];
  #pragma unroll
  for (int e = 0; e < 8; ++e) h[e] = rne16(f[e]);
  return make_uint4(h[0]|(h[1]<<16), h[2]|(h[3]<<16), h[4]|(h[5]<<16), h[6]|(h[7]<<16));
}

// ---------------- FUSED layernorm + A-presplit (2-plane RNE, pre-swizzled) -------
__global__ __launch_bounds__(256) void lnsplit_kernel(
    const float* __restrict__ x, const float* __restrict__ g,
    const float* __restrict__ b, uint4* __restrict__ outp) {
  __shared__ float red[8];
  __shared__ float rowbuf[1024];
  int row = blockIdx.x, tid = threadIdx.x;
  float4 v = reinterpret_cast<const float4*>(x)[(size_t)row * (CC/4) + tid];
  float s  = v.x+v.y+v.z+v.w;
  float ss = v.x*v.x+v.y*v.y+v.z*v.z+v.w*v.w;
  #pragma unroll
  for (int off = 32; off; off >>= 1) { s += __shfl_xor(s, off); ss += __shfl_xor(ss, off); }
  if ((tid & 63) == 0) { red[tid>>6] = s; red[4+(tid>>6)] = ss; }
  __syncthreads();
  s  = red[0]+red[1]+red[2]+red[3];
  ss = red[4]+red[5]+red[6]+red[7];
  float mu = s * (1.f/CC);
  float rs = rsqrtf(ss*(1.f/CC) - mu*mu + 1e-5f);
  float4 gg = reinterpret_cast<const float4*>(g)[tid];
  float4 bb = reinterpret_cast<const float4*>(b)[tid];
  float4 o;
  o.x = (v.x-mu)*rs*gg.x + bb.x;
  o.y = (v.y-mu)*rs*gg.y + bb.y;
  o.z = (v.z-mu)*rs*gg.z + bb.z;
  o.w = (v.w-mu)*rs*gg.w + bb.w;
  *reinterpret_cast<float4*>(&rowbuf[tid*4]) = o;
  __syncthreads();
  if (tid < 128) {
    const size_t aPS = (size_t)128 * 16 * 512;
    int kt = tid >> 3, sl = tid & 7;
    int r = row & 63, mt = row >> 6;
    float f[8];
    #pragma unroll
    for (int e = 0; e < 8; ++e) f[e] = rowbuf[tid*8 + e];
    size_t di = ((size_t)(mt*16 + kt))*512 + r*8 + (sl ^ (r & 7));
    Oct2 ot = split8_rne2(f);
    outp[di] = ot.p0; outp[aPS+di] = ot.p1;
  }
}

// ---------------- FUSED layernorm + 1-plane presplit (final LN / logits) ---------
__global__ __launch_bounds__(256) void lnsplit1_kernel(
    const float* __restrict__ x, const float* __restrict__ g,
    const float* __restrict__ b, uint4* __restrict__ outp) {
  __shared__ float red[8];
  __shared__ float rowbuf[1024];
  int row = blockIdx.x, tid = threadIdx.x;
  float4 v = reinterpret_cast<const float4*>(x)[(size_t)row * (CC/4) + tid];
  float s  = v.x+v.y+v.z+v.w;
  float ss = v.x*v.x+v.y*v.y+v.z*v.z+v.w*v.w;
  #pragma unroll
  for (int off = 32; off; off >>= 1) { s += __shfl_xor(s, off); ss += __shfl_xor(ss, off); }
  if ((tid & 63) == 0) { red[tid>>6] = s; red[4+(tid>>6)] = ss; }
  __syncthreads();
  s  = red[0]+red[1]+red[2]+red[3];
  ss = red[4]+red[5]+red[6]+red[7];
  float mu = s * (1.f/CC);
  float rs = rsqrtf(ss*(1.f/CC) - mu*mu + 1e-5f);
  float4 gg = reinterpret_cast<const float4*>(g)[tid];
  float4 bb = reinterpret_cast<const float4*>(b)[tid];
  float4 o;
  o.x = (v.x-mu)*rs*gg.x + bb.x;
  o.y = (v.y-mu)*rs*gg.y + bb.y;
  o.z = (v.z-mu)*rs*gg.z + bb.z;
  o.w = (v.w-mu)*rs*gg.w + bb.w;
  *reinterpret_cast<float4*>(&rowbuf[tid*4]) = o;
  __syncthreads();
  if (tid < 128) {
    int kt = tid >> 3, sl = tid & 7;
    int r = row & 63, mt = row >> 6;
    float f[8];
    #pragma unroll
    for (int e = 0; e < 8; ++e) f[e] = rowbuf[tid*8 + e];
    size_t di = ((size_t)(mt*16 + kt))*512 + r*8 + (sl ^ (r & 7));
    outp[di] = pack8_rne(f);
  }
}

// ------- fused B pre-split: Wq/Wk/Wv -> combined 24-tile buffer; Wo separate ------
__global__ __launch_bounds__(256) void bsplit4_kernel(
    const float* __restrict__ Wq, const float* __restrict__ Wk,
    const float* __restrict__ Wv, const float* __restrict__ Wo,
    uint4* __restrict__ bsQKV, uint4* __restrict__ bsO) {
  int z = blockIdx.z;
  const float* Bw = (z == 0) ? Wq : (z == 1) ? Wk : (z == 2) ? Wv : Wo;
  uint4* outp = (z <= 2) ? bsQKV : bsO;
  int ntile0 = (z <= 2) ? z*8 : 0;
  size_t planeStride = (z <= 2) ? (size_t)24 * 16 * 1024 : (size_t)8 * 16 * 1024;
  int ntile = ntile0 + blockIdx.x, kt = blockIdx.y;
  int tid = threadIdx.x;
  int bcol = tid & 127, bkcg = tid >> 7;
  #pragma unroll
  for (int g = 0; g < 4; ++g) {
    int kc = bkcg*4 + g;
    float f[8];
    #pragma unroll
    for (int j = 0; j < 8; ++j)
      f[j] = Bw[(size_t)(kt*64 + kc*8 + j) * CC + blockIdx.x*128 + bcol];
    size_t di = (((size_t)ntile * 16 + kt) * 8 + kc) * 128 + bcol;
    Oct2 o = split8_rne2(f);
    outp[di] = o.p0; outp[planeStride+di] = o.p1;
  }
}

// ---------------- B pre-split (W1/W2/logits) ----------------
template<int NP>
__global__ __launch_bounds__(256) void bsplit_kernel(
    const float* __restrict__ Bw, uint4* __restrict__ outp, int ldb,
    int ntile0, int ntTotal) {
  int ntile = ntile0 + blockIdx.x, kt = blockIdx.y;
  size_t planeStride = (size_t)ntTotal * gridDim.y * 1024;
  int tid = threadIdx.x;
  int bcol = tid & 127, bkcg = tid >> 7;
  #pragma unroll
  for (int g = 0; g < 4; ++g) {
    int kc = bkcg*4 + g;
    float f[8];
    #pragma unroll
    for (int j = 0; j < 8; ++j)
      f[j] = Bw[(size_t)(kt*64 + kc*8 + j) * ldb + blockIdx.x*128 + bcol];
    size_t di = (((size_t)ntile * gridDim.y + kt) * 8 + kc) * 128 + bcol;
    if (NP == 2) {
      Oct2 o = split8_rne2(f);
      outp[di] = o.p0; outp[planeStride+di] = o.p1;
    } else {
      outp[di] = pack8_rne(f);
    }
  }
}

// ---------------- 128x128 GEMM, global_load_lds staging, XCD-grouped grid -------
// vtmode 3 (fused QKV): ntg<8 -> q fp32; 8..15 -> K attn-tiles; >=16 -> V planes.
template<int NP, bool ASP, int NM>
__global__ __launch_bounds__(256) void gemm128_kernel(
    const float* __restrict__ A, int lda,
    const uint4* __restrict__ Asp, size_t aPS,
    const uint4* __restrict__ Bs,
    const float* __restrict__ bias, const float* __restrict__ res,
    float* __restrict__ outf, int K, int ldc, int relu,
    int ntile0, int ntTotal, int kt0, int ktTotal, int vtmode,
    uint4* __restrict__ kout, uint4* __restrict__ vout) {
  __shared__ uint4 lds_all[NP*2048];
  uint4* lds_a = lds_all;
  uint4* lds_b = lds_all + NP*1024;
  int tid = threadIdx.x;
  int NYd8 = gridDim.y >> 3;
  int li = blockIdx.x + gridDim.x * blockIdx.y;
  int xcd = li & 7, j = li >> 3;
  int by = xcd + 8 * (j % NYd8);
  int bx = j / NYd8;
  int m0 = by * 128;
  int n0 = bx * 128;
  int ntg = ntile0 + bx;
  size_t bPS = (size_t)ntTotal * ktTotal * 1024;
  int lane = tid & 63, w = tid >> 6;
  int wm = w >> 1, wn = w & 1;
  int lr = lane & 15, lk = lane >> 4;
  int nkt = K >> 6;

  f32x4 acc[4][4];
  #pragma unroll
  for (int m = 0; m < 4; ++m)
    #pragma unroll
    for (int n = 0; n < 4; ++n)
      acc[m][n] = (f32x4){0.f, 0.f, 0.f, 0.f};

  for (int kt = 0; kt < nkt; ++kt) {
    if (ASP) {
      #pragma unroll
      for (int p = 0; p < NP; ++p) {
        const uint4* s0 = Asp + p*aPS + ((size_t)(2*by)   * nkt + kt)*512;
        const uint4* s1 = Asp + p*aPS + ((size_t)(2*by+1) * nkt + kt)*512;
        #pragma unroll
        for (int i = 0; i < 2; ++i) {
          int ch = w*2 + i;
          gld16(s0 + ch*64 + lane, &lds_a[p*1024 + ch*64]);
          gld16(s1 + ch*64 + lane, &lds_a[p*1024 + 512 + ch*64]);
        }
      }
    } else {
      #pragma unroll
      for (int i = 0; i < 4; ++i) {
        int c = tid + i * 256;
        int row = c >> 3, sl = c & 7;
        const float4* ap = reinterpret_cast<const float4*>(
            A + (size_t)(m0+row)*lda + kt*64 + sl*8);
        float4 x0 = ap[0], x1 = ap[1];
        float f[8] = {x0.x,x0.y,x0.z,x0.w,x1.x,x1.y,x1.z,x1.w};
        int di = (row>>6)*512 + (row&63)*8 + (sl ^ (row & 7));
        if (NP == 2) {
          Oct2 o = split8_rne2(f);
          lds_a[di] = o.p0; lds_a[1024 + di] = o.p1;
        } else {
          lds_a[di] = pack8_rne(f);
        }
      }
    }
    {
      int ktg = kt0 + kt;
      #pragma unroll
      for (int p = 0; p < NP; ++p) {
        const uint4* sb = Bs + p*bPS + ((size_t)ntg * ktTotal + ktg)*1024;
        #pragma unroll
        for (int i = 0; i < 4; ++i) {
          int ch = w*4 + i;
          gld16(sb + ch*64 + lane, &lds_b[p*1024 + ch*64]);
        }
      }
    }
    __syncthreads();
    #pragma unroll
    for (int ks = 0; ks < 2; ++ks) {
      int kc = ks*4 + lk;
      bf16x8 af[NP][4], bfr[NP][4];
      #pragma unroll
      for (int m = 0; m < 4; ++m) {
        int row = wm*64 + m*16 + lr;
        int si = (row>>6)*512 + (row&63)*8 + (kc ^ (row & 7));
        #pragma unroll
        for (int p = 0; p < NP; ++p)
          af[p][m] = reinterpret_cast<const bf16x8*>(lds_a + p*1024)[si];
      }
      #pragma unroll
      for (int n = 0; n < 4; ++n) {
        int si = kc*128 + wn*64 + n*16 + lr;
        #pragma unroll
        for (int p = 0; p < NP; ++p)
          bfr[p][n] = reinterpret_cast<const bf16x8*>(lds_b + p*1024)[si];
      }
      #pragma unroll
      for (int m = 0; m < 4; ++m)
        #pragma unroll
        for (int n = 0; n < 4; ++n) {
          acc[m][n] = __builtin_amdgcn_mfma_f32_16x16x32_bf16(af[0][m], bfr[0][n], acc[m][n], 0, 0, 0);
          if (NP == 2) {
            acc[m][n] = __builtin_amdgcn_mfma_f32_16x16x32_bf16(af[0][m], bfr[1][n], acc[m][n], 0, 0, 0);
            acc[m][n] = __builtin_amdgcn_mfma_f32_16x16x32_bf16(af[1][m], bfr[0][n], acc[m][n], 0, 0, 0);
            if (NM == 4)
              acc[m][n] = __builtin_amdgcn_mfma_f32_16x16x32_bf16(af[1][m], bfr[1][n], acc[m][n], 0, 0, 0);
          }
        }
    }
    __syncthreads();
  }

  if (vtmode == 3 && ntg >= 16) {
    // V projection -> 2-plane attn-tile planes (local col base (ntg-16)*128)
    char* vb = (char*)vout;
    const size_t VPSb = (size_t)2048 * 512 * 16;
    #pragma unroll
    for (int m = 0; m < 4; ++m) {
      int row = m0 + wm*64 + m*16 + lk*4;
      int bq = row >> 10;
      int t  = row & (TT-1);
      int ktile = t >> 6, r = t & 63;
      int kc = r >> 3, toct0 = r & 7;
      #pragma unroll
      for (int n = 0; n < 4; ++n) {
        int col = (ntg-16)*128 + wn*64 + n*16 + lr;
        int hh2 = col >> 6, d = col & 63;
        int tile = (bq*HH + hh2)*16 + ktile;
        int vi = kc*64 + ((d ^ (kc<<1)) & 63);
        unsigned p0[4], p1[4];
        #pragma unroll
        for (int j2 = 0; j2 < 4; ++j2) {
          float v = acc[m][n][j2];
          p0[j2] = rne16(v);
          p1[j2] = rne16(v - bf2f((unsigned short)p0[j2]));
        }
        uint2 w0 = make_uint2(p0[0]|(p0[1]<<16), p0[2]|(p0[3]<<16));
        uint2 w1 = make_uint2(p1[0]|(p1[1]<<16), p1[2]|(p1[3]<<16));
        char* base = vb + ((size_t)tile*512 + vi)*16 + toct0*2;
        *reinterpret_cast<uint2*>(base) = w0;
        *reinterpret_cast<uint2*>(base + VPSb) = w1;
      }
    }
  } else if (vtmode == 2) {
    float* bounce = (float*)lds_all;
    #pragma unroll
    for (int m = 0; m < 4; ++m)
      #pragma unroll
      for (int n = 0; n < 4; ++n) {
        int cl = wn*64 + n*16 + lr;
        float bv = bias[n0 + cl];
        #pragma unroll
        for (int j2 = 0; j2 < 4; ++j2) {
          int rl = wm*64 + m*16 + lk*4 + j2;
          bounce[rl*128 + cl] = fmaxf(acc[m][n][j2] + bv, 0.f);
        }
      }
    __syncthreads();
    uint4* a1p = (uint4*)outf;
    const size_t aPSa = (size_t)128 * 32 * 512;
    #pragma unroll
    for (int i = 0; i < 8; ++i) {
      int ot = tid + i*256;
      int r = ot >> 4, o = ot & 15;
      float f[8];
      #pragma unroll
      for (int e = 0; e < 8; ++e) f[e] = bounce[r*128 + o*8 + e];
      Oct2 o2 = split8_rne2(f);
      int mt = 2*by + (r>>6), rs = r & 63;
      int ktg = (n0 >> 6) + (o >> 3), sl = o & 7;
      size_t di = ((size_t)(mt*32 + ktg))*512 + rs*8 + (sl ^ (rs & 7));
      a1p[di] = o2.p0; a1p[aPSa + di] = o2.p1;
    }
  } else if (vtmode == 3 && ntg >= 8) {
    float* bounce = (float*)lds_all;
    #pragma unroll
    for (int m = 0; m < 4; ++m)
      #pragma unroll
      for (int n = 0; n < 4; ++n) {
        int cl = wn*64 + n*16 + lr;
        #pragma unroll
        for (int j2 = 0; j2 < 4; ++j2) {
          int rl = wm*64 + m*16 + lk*4 + j2;
          bounce[rl*128 + cl] = acc[m][n][j2];
        }
      }
    __syncthreads();
    const size_t KPSC = (size_t)2048 * 512;
    int bq = m0 >> 10;
    int kt0tok = (m0 & 1023) >> 6;
    int hh0 = (ntg - 8) * 2;
    #pragma unroll
    for (int i = 0; i < 8; ++i) {
      int u = tid + i*256;
      int r = u >> 4, oct = u & 15;
      int head = oct >> 3, sl = oct & 7;
      float f[8];
      #pragma unroll
      for (int e = 0; e < 8; ++e) f[e] = bounce[r*128 + head*64 + sl*8 + e];
      Oct2 o = split8_rne2(f);
      int rk = r & 63;
      int tile = (bq*HH + hh0 + head)*16 + kt0tok + (r >> 6);
      size_t di = (size_t)tile*512 + rk*8 + (sl ^ (rk & 7));
      kout[di] = o.p0; kout[KPSC + di] = o.p1;
    }
  } else {
    #pragma unroll
    for (int m = 0; m < 4; ++m) {
      #pragma unroll
      for (int n = 0; n < 4; ++n) {
        int col = n0 + wn*64 + n*16 + lr;
        float bv = bias ? bias[col] : 0.f;
        #pragma unroll
        for (int j2 = 0; j2 < 4; ++j2) {
          int row = m0 + wm*64 + m*16 + lk*4 + j2;
          float vv = acc[m][n][j2] + bv;
          if (relu) vv = fmaxf(vv, 0.f);
          size_t off = (size_t)row * ldc + col;
          if (res) vv += res[off];
          outf[off] = vv;
        }
      }
    }
  }
}

// ---------------- MFMA flash attention (R22/R24-proven, unchanged) -------
__global__ __launch_bounds__(256) void attn_mfma_kernel(
    const float* __restrict__ qf, const uint4* __restrict__ Kp,
    const uint4* __restrict__ Vp, uint4* __restrict__ aout) {
  __shared__ uint4 K_lds[2][512];
  __shared__ uint4 V_lds[2][512];
  __shared__ unsigned P_lds[64*68];
  const size_t KPS = (size_t)2048 * 512;
  const size_t VPS = (size_t)2048 * 512;
  const size_t APS = (size_t)128 * 16 * 512;
  int tid = threadIdx.x, lane = tid & 63, w = tid >> 6;
  int i = blockIdx.x;
  int xcd = i & 7, qm = (i >> 3) & 15, ghi = i >> 7;
  int g = ghi*8 + xcd;
  int b = g >> 4, hh = g & 15, qt = 15 - qm;
  int lr = lane & 15, lk = lane >> 4;
  const size_t tok0 = (size_t)b * TT;
  const int tbase = (b*HH + hh)*16;

  bf16x8 qa[2][2];
  {
    const float* qp = qf + (tok0 + qt*64 + w*16 + lr) * 1024 + hh*HS;
    #pragma unroll
    for (int ks = 0; ks < 2; ++ks) {
      const float4* p4 = reinterpret_cast<const float4*>(qp + ks*32 + lk*8);
      float4 a = p4[0], c = p4[1];
      float f[8] = {a.x,a.y,a.z,a.w,c.x,c.y,c.z,c.w};
      Oct2 ot = split8_rne2(f);
      qa[ks][0] = *reinterpret_cast<bf16x8*>(&ot.p0);
      qa[ks][1] = *reinterpret_cast<bf16x8*>(&ot.p1);
    }
  }

  float mrow[4] = {-3.0e38f,-3.0e38f,-3.0e38f,-3.0e38f};
  float lrow[4] = {0.f,0.f,0.f,0.f};
  f32x4 oac[4];
  #pragma unroll
  for (int n = 0; n < 4; ++n) oac[n] = (f32x4){0.f,0.f,0.f,0.f};

  {
    const uint4* ksrc = Kp + (size_t)tbase*512;
    const uint4* vsrc = Vp + (size_t)tbase*512;
    #pragma unroll
    for (int p = 0; p < 2; ++p)
      #pragma unroll
      for (int i2 = 0; i2 < 2; ++i2) {
        int ch = w*2 + i2;
        gld16(ksrc + p*KPS + ch*64 + lane, &K_lds[p][ch*64]);
        gld16(vsrc + p*VPS + ch*64 + lane, &V_lds[p][ch*64]);
      }
  }

  for (int kt = 0; kt <= qt; ++kt) {
    __syncthreads();

    f32x4 sfr[4];
    #pragma unroll
    for (int nf = 0; nf < 4; ++nf) sfr[nf] = (f32x4){0.f,0.f,0.f,0.f};
    __builtin_amdgcn_s_setprio(1);
    #pragma unroll
    for (int ks = 0; ks < 2; ++ks) {
      int kc = ks*4 + lk;
      #pragma unroll
      for (int nf = 0; nf < 4; ++nf) {
        int row = nf*16 + lr;
        int si = row*8 + (kc ^ (row & 7));
        bf16x8 k0 = *reinterpret_cast<const bf16x8*>(&K_lds[0][si]);
        bf16x8 k1 = *reinterpret_cast<const bf16x8*>(&K_lds[1][si]);
        sfr[nf] = __builtin_amdgcn_mfma_f32_16x16x32_bf16(qa[ks][0], k0, sfr[nf], 0,0,0);
        sfr[nf] = __builtin_amdgcn_mfma_f32_16x16x32_bf16(qa[ks][0], k1, sfr[nf], 0,0,0);
        sfr[nf] = __builtin_amdgcn_mfma_f32_16x16x32_bf16(qa[ks][1], k0, sfr[nf], 0,0,0);
      }
    }
    __builtin_amdgcn_s_setprio(0);
    RAWBAR();

    if (kt < qt) {
      const uint4* ksrc = Kp + (size_t)(tbase + kt + 1)*512;
      #pragma unroll
      for (int p = 0; p < 2; ++p)
        #pragma unroll
        for (int i2 = 0; i2 < 2; ++i2) {
          int ch = w*2 + i2;
          gld16(ksrc + p*KPS + ch*64 + lane, &K_lds[p][ch*64]);
        }
    }

    #pragma unroll
    for (int nf = 0; nf < 4; ++nf)
      #pragma unroll
      for (int j = 0; j < 4; ++j) {
        float s = sfr[nf][j] * 8.0f;
        if (kt == qt && (nf*16 + lr) > (w*16 + lk*4 + j)) s = -3.0e38f;
        sfr[nf][j] = s;
      }
    float alpha[4], tsum[4];
    #pragma unroll
    for (int j = 0; j < 4; ++j) {
      float mx = fmaxf(fmaxf(sfr[0][j], sfr[1][j]), fmaxf(sfr[2][j], sfr[3][j]));
      mx = fmaxf(mx, __shfl_xor(mx, 1));
      mx = fmaxf(mx, __shfl_xor(mx, 2));
      mx = fmaxf(mx, __shfl_xor(mx, 4));
      mx = fmaxf(mx, __shfl_xor(mx, 8));
      float mnew = fmaxf(mrow[j], mx);
      alpha[j] = __expf(mrow[j] - mnew);
      mrow[j] = mnew;
      tsum[j] = 0.f;
    }
    #pragma unroll
    for (int nf = 0; nf < 4; ++nf)
      #pragma unroll
      for (int j = 0; j < 4; ++j) {
        float p = __expf(sfr[nf][j] - mrow[j]);
        tsum[j] += p;
        unsigned u = __float_as_uint(p);
        float r = p - __uint_as_float(u & 0xffff0000u);
        unsigned pw = (u & 0xffff0000u) | (__float_as_uint(r) >> 16);
        int qrow = w*16 + lk*4 + j;
        int kcol = nf*16 + lr;
        P_lds[qrow*68 + (((kcol>>3) ^ (qrow & 7)))*8 + (kcol & 7)] = pw;
      }
    #pragma unroll
    for (int j = 0; j < 4; ++j) {
      float ts = tsum[j];
      ts += __shfl_xor(ts, 1);
      ts += __shfl_xor(ts, 2);
      ts += __shfl_xor(ts, 4);
      ts += __shfl_xor(ts, 8);
      lrow[j] = lrow[j]*alpha[j] + ts;
      oac[0][j] *= alpha[j]; oac[1][j] *= alpha[j];
      oac[2][j] *= alpha[j]; oac[3][j] *= alpha[j];
    }
    RAWBAR();

    __builtin_amdgcn_s_setprio(1);
    #pragma unroll
    for (int ks = 0; ks < 2; ++ks) {
      int kc = ks*4 + lk;
      int prow = w*16 + lr;
      const uint4* pp4 = reinterpret_cast<const uint4*>(
          &P_lds[prow*68 + ((kc ^ (prow & 7)))*8]);
      uint4 pw0 = pp4[0], pw1 = pp4[1];
      uint4 phu, plu;
      phu.x = (pw0.x>>16) | (pw0.y & 0xffff0000u);
      phu.y = (pw0.z>>16) | (pw0.w & 0xffff0000u);
      phu.z = (pw1.x>>16) | (pw1.y & 0xffff0000u);
      phu.w = (pw1.z>>16) | (pw1.w & 0xffff0000u);
      plu.x = (pw0.x & 0xffffu) | (pw0.y << 16);
      plu.y = (pw0.z & 0xffffu) | (pw0.w << 16);
      plu.z = (pw1.x & 0xffffu) | (pw1.y << 16);
      plu.w = (pw1.z & 0xffffu) | (pw1.w << 16);
      bf16x8 ph = *reinterpret_cast<bf16x8*>(&phu);
      bf16x8 pl = *reinterpret_cast<bf16x8*>(&plu);
      #pragma unroll
      for (int nf2 = 0; nf2 < 4; ++nf2) {
        int d = nf2*16 + lr;
        int vi = kc*64 + ((d ^ (kc<<1)) & 63);
        bf16x8 vh = *reinterpret_cast<const bf16x8*>(&V_lds[0][vi]);
        bf16x8 vl = *reinterpret_cast<const bf16x8*>(&V_lds[1][vi]);
        oac[nf2] = __builtin_amdgcn_mfma_f32_16x16x32_bf16(ph, vh, oac[nf2], 0,0,0);
        oac[nf2] = __builtin_amdgcn_mfma_f32_16x16x32_bf16(ph, vl, oac[nf2], 0,0,0);
        oac[nf2] = __builtin_amdgcn_mfma_f32_16x16x32_bf16(pl, vh, oac[nf2], 0,0,0);
      }
    }
    __builtin_amdgcn_s_setprio(0);
    if (kt < qt) {
      RAWBAR();
      const uint4* vsrc = Vp + (size_t)(tbase + kt + 1)*512;
      #pragma unroll
      for (int p = 0; p < 2; ++p)
        #pragma unroll
        for (int i2 = 0; i2 < 2; ++i2) {
          int ch = w*2 + i2;
          gld16(vsrc + p*VPS + ch*64 + lane, &V_lds[p][ch*64]);
        }
    }
  }

  __syncthreads();
  float* Pf = (float*)P_lds;
  #pragma unroll
  for (int j = 0; j < 4; ++j) {
    float inv = 1.0f / lrow[j];
    #pragma unroll
    for (int nf2 = 0; nf2 < 4; ++nf2)
      Pf[(w*16 + lk*4 + j)*68 + nf2*16 + lr] = oac[nf2][j] * inv;
  }
  __syncthreads();
  int mtkt = (b*16 + qt)*16 + hh;
  #pragma unroll
  for (int i2 = 0; i2 < 2; ++i2) {
    int u = tid + i2*256;
    int r = u >> 3, sl = u & 7;
    float f[8];
    #pragma unroll
    for (int e = 0; e < 8; ++e) f[e] = Pf[r*68 + sl*8 + e];
    Oct2 o = split8_rne2(f);
    size_t di = (size_t)mtkt*512 + r*8 + (sl ^ (r & 7));
    aout[di] = o.p0; aout[APS + di] = o.p1;
  }
}

extern "C" void kernel_launch(void* const* d_in, const int* in_sizes, int n_in,
                              void* d_out, int out_size, void* d_ws, size_t ws_size,
                              hipStream_t stream) {
  const int*   idx  = (const int*)d_in[0];
  const float* tok  = (const float*)d_in[1];
  const float* pos  = (const float*)d_in[2];
  const float* Wq   = (const float*)d_in[3];
  const float* Wk   = (const float*)d_in[4];
  const float* Wv   = (const float*)d_in[5];
  const float* Wo   = (const float*)d_in[6];
  const float* bo   = (const float*)d_in[7];
  const float* ln1g = (const float*)d_in[8];
  const float* ln1b = (const float*)d_in[9];
  const float* ln2g = (const float*)d_in[10];
  const float* ln2b = (const float*)d_in[11];
  const float* W1   = (const float*)d_in[12];
  const float* b1   = (const float*)d_in[13];
  const float* W2   = (const float*)d_in[14];
  const float* b2   = (const float*)d_in[15];
  const float* lnfg = (const float*)d_in[16];
  const float* lnfb = (const float*)d_in[17];
  const float* lmw  = (const float*)d_in[18];
  const float* lmb  = (const float*)d_in[19];
  float* out = (float*)d_out;

  // d_out: x[0,32M) | vplanes[32,64M) | qf[64,96M) | Kp 2pl [96,128M);
  //        a1p reuses [64,128M) during MLP. Logits overwrite all at end.
  // ws: aspH[0,32) | bsQKV (24-tile, 2pl) [32,44) | bsO [44,48)
  //     aspH2 (attn out) [0,32); aspH3 [0,32); bsW1 [32,48) | bsW2 [48,64);
  //     final: hfp 1-plane [0,16) | bsL [32,40).
  char* ob = (char*)d_out;
  float* x  = (float*)ob;
  float* vplanes = (float*)(ob + ((size_t)32<<20));
  float* qf = (float*)(ob + ((size_t)64<<20));
  uint4* Kp = (uint4*)(ob + ((size_t)96<<20));
  float* a1p = (float*)(ob + ((size_t)64<<20));
  char* wsb = (char*)d_ws;
  uint4* aspH  = (uint4*)wsb;
  uint4* bsQKV = (uint4*)(wsb + ((size_t)32<<20));
  uint4* bsO   = (uint4*)(wsb + ((size_t)44<<20));
  uint4* aspH2 = (uint4*)wsb;
  uint4* aspH3 = (uint4*)wsb;
  uint4* bsW1  = (uint4*)(wsb + ((size_t)32<<20));
  uint4* bsW2  = (uint4*)(wsb + ((size_t)48<<20));
  uint4* hfp   = (uint4*)wsb;
  uint4* bsL   = (uint4*)(wsb + ((size_t)32<<20));
  const size_t aPSh = (size_t)128 * 16 * 512;
  const size_t aPSa = (size_t)128 * 32 * 512;

  dim3 blk(256);
  dim3 gQKV(24, 64), gO(8, 64);
  dim3 gW1(16, 64), gW2(8, 64), gL(32, 64);
  dim3 s4(8, 16, 4), sW1(32, 16), sW2(8, 64), sLM(32, 16);

  embed_kernel<<<BT, blk, 0, stream>>>(idx, tok, pos, x);
  for (int l = 0; l < LL; ++l) {
    const float* Wq_l = Wq + (size_t)l*CC*CC;
    const float* Wk_l = Wk + (size_t)l*CC*CC;
    const float* Wv_l = Wv + (size_t)l*CC*CC;
    const float* Wo_l = Wo + (size_t)l*CC*CC;
    const float* W1_l = W1 + (size_t)l*CC*4*CC;
    const float* W2_l = W2 + (size_t)l*4*CC*CC;
    lnsplit_kernel<<<BT, blk, 0, stream>>>(x, ln1g + (size_t)l*CC, ln1b + (size_t)l*CC, aspH);
    bsplit4_kernel<<<s4, blk, 0, stream>>>(Wq_l, Wk_l, Wv_l, Wo_l, bsQKV, bsO);
    gemm128_kernel<2,true,3><<<gQKV, blk, 0, stream>>>(nullptr, 0, aspH, aPSh, bsQKV,
        nullptr, nullptr, qf, CC, 1024, 0, 0, 24, 0, 16, 3, Kp, (uint4*)vplanes);
    attn_mfma_kernel<<<BB*HH*16, blk, 0, stream>>>(qf, Kp, (const uint4*)vplanes, aspH2);
    gemm128_kernel<2,true,3><<<gO, blk, 0, stream>>>(nullptr, 0, aspH2, aPSh, bsO,
        bo + (size_t)l*CC, x, x, CC, CC, 0, 0, 8, 0, 16, 0, nullptr, nullptr);
    lnsplit_kernel<<<BT, blk, 0, stream>>>(x, ln2g + (size_t)l*CC, ln2b + (size_t)l*CC, aspH3);
    bsplit_kernel<2><<<sW1, blk, 0, stream>>>(W1_l, bsW1, 4*CC, 0, 32);
    bsplit_kernel<2><<<sW2, blk, 0, stream>>>(W2_l, bsW2, CC, 0, 8);
    gemm128_kernel<2,true,3><<<gW1, blk, 0, stream>>>(nullptr, 0, aspH3, aPSh, bsW1,
        b1 + (size_t)l*4*CC, nullptr, a1p, CC, 2048, 1, 0, 32, 0, 16, 2, nullptr, nullptr);
    gemm128_kernel<2,true,3><<<gW2, blk, 0, stream>>>(nullptr, 0, (const uint4*)a1p, aPSa, bsW2,
        b2 + (size_t)l*CC, x, x, 2048, CC, 0, 0, 8, 0, 64, 0, nullptr, nullptr);
    gemm128_kernel<2,true,3><<<gW1, blk, 0, stream>>>(nullptr, 0, aspH3, aPSh, bsW1,
        b1 + (size_t)l*4*CC + 2048, nullptr, a1p, CC, 2048, 1, 16, 32, 0, 16, 2, nullptr, nullptr);
    gemm128_kernel<2,true,3><<<gW2, blk, 0, stream>>>(nullptr, 0, (const uint4*)a1p, aPSa, bsW2,
        nullptr, x, x, 2048, CC, 0, 0, 8, 32, 64, 0, nullptr, nullptr);
  }
  lnsplit1_kernel<<<BT, blk, 0, stream>>>(x, lnfg, lnfb, hfp);
  bsplit_kernel<1><<<sLM, blk, 0, stream>>>(lmw, bsL, VV, 0, 32);
  gemm128_kernel<1,true,1><<<gL, blk, 0, stream>>>(nullptr, 0, hfp, aPSh, bsL,
      lmb, nullptr, out, CC, VV, 0, 0, 32, 0, 16, 0, nullptr, nullptr);
}